// Round 15
// baseline (320.620 us; speedup 1.0000x reference)
//
#include <hip/hip_runtime.h>

#define NB 8
#define CIN 512
#define OIN 256
#define HWN 9216
#define KP 110
#define SCL 0.10206207261596577f  // 9216^(-0.25)

typedef __attribute__((ext_vector_type(8))) short bf16x8;
typedef __attribute__((ext_vector_type(4))) float f32x4;
typedef unsigned short u16;

__device__ inline unsigned bf16_1(float a) {
    unsigned u = __builtin_bit_cast(unsigned, a);
    return (u + 0x7fffu + ((u >> 16) & 1u)) >> 16;
}
__device__ inline unsigned bf16_pack(float a, float b) {
    return bf16_1(a) | (bf16_1(b) << 16);
}
__device__ inline float b2f(u16 u) {
    return __builtin_bit_cast(float, ((unsigned)u) << 16);
}

__device__ __forceinline__ void gload16(const u16* g, u16* l) {
    __builtin_amdgcn_global_load_lds(
        (const __attribute__((address_space(1))) unsigned int*)g,
        (__attribute__((address_space(3))) unsigned int*)l, 16, 0, 0);
}

// ---------------------------------------------------------------------------
// Weight cast: phi_w+theta_w -> Wcat bf16 [512][512]; W_w -> Wwb bf16 [512][256]
// ---------------------------------------------------------------------------
__global__ __launch_bounds__(256) void castw_kernel(
    const float* __restrict__ phi_w, const float* __restrict__ theta_w,
    const float* __restrict__ Ww,
    u16* __restrict__ Wcat, u16* __restrict__ Wwb)
{
    int i = blockIdx.x * 256 + threadIdx.x;
    if (i < 262144) {
        float v = (i < 131072) ? phi_w[i] : theta_w[i - 131072];
        Wcat[i] = (u16)bf16_1(v);
    } else {
        int j = i - 262144;
        Wwb[j] = (u16)bf16_1(Ww[j]);
    }
}

// ---------------------------------------------------------------------------
// castx: x fp32 [b][512 c][9216 hw] -> xT bf16 [b][9216 hw][512 c]
// ---------------------------------------------------------------------------
__global__ __launch_bounds__(256) void castx_kernel(
    const float* __restrict__ x, u16* __restrict__ xT)
{
    const int t = threadIdx.x;
    const int tx = t & 15, ty = t >> 4;
    const int b = blockIdx.z;
    const int c0 = blockIdx.y * 64;
    const int hw0 = blockIdx.x * 64;

    const float* xb = x + ((size_t)b * CIN + c0 + ty * 4) * HWN + hw0 + tx * 4;
    float4 v[4];
#pragma unroll
    for (int q = 0; q < 4; ++q)
        v[q] = *(const float4*)(xb + (size_t)q * HWN);

    u16* dst = xT + ((size_t)b * HWN + hw0 + tx * 4) * CIN + c0 + ty * 4;
    const float* f = (const float*)v;
#pragma unroll
    for (int p = 0; p < 4; ++p) {
        uint2 o = {bf16_pack(f[0 * 4 + p], f[1 * 4 + p]),
                   bf16_pack(f[2 * 4 + p], f[3 * 4 + p])};
        *(uint2*)(dst + (size_t)p * CIN) = o;
    }
}

// ---------------------------------------------------------------------------
// poolx stage A: xT bf16 -> 4x4 block sums bs[b][512 c][576 blk] fp32.
// Block = (bh, b): rows h in [bh*4, bh*4+4), all w, all c. Reads are
// 1KB-contiguous per wave (64 lanes x 16B over c). 75.5 MB total (vs 151
// MB fp32 re-read of x) and L3-hot right after castx.
// ---------------------------------------------------------------------------
__global__ __launch_bounds__(256) void poolx_bs_kernel(
    const u16* __restrict__ xT,   // [B][9216][512]
    float* __restrict__ bs)       // [B][512][576]
{
    __shared__ float sm[4][512];
    const int bh = blockIdx.x, b = blockIdx.y;
    const int t = threadIdx.x;
    const int g = t >> 6;            // h within the 4-row group
    const int co = (t & 63) * 8;     // c octet

#pragma unroll 1
    for (int bw = 0; bw < 24; ++bw) {
        float a[8] = {0.f, 0.f, 0.f, 0.f, 0.f, 0.f, 0.f, 0.f};
        const int hwbase = (bh * 4 + g) * 96 + bw * 4;
        const u16* base = xT + ((size_t)b * HWN + hwbase) * CIN + co;
#pragma unroll
        for (int wI = 0; wI < 4; ++wI) {
            uint4 v = *(const uint4*)(base + (size_t)wI * CIN);
            a[0] += b2f((u16)v.x); a[1] += b2f((u16)(v.x >> 16));
            a[2] += b2f((u16)v.y); a[3] += b2f((u16)(v.y >> 16));
            a[4] += b2f((u16)v.z); a[5] += b2f((u16)(v.z >> 16));
            a[6] += b2f((u16)v.w); a[7] += b2f((u16)(v.w >> 16));
        }
#pragma unroll
        for (int j = 0; j < 8; ++j) sm[g][co + j] = a[j];
        __syncthreads();
        {
            int c2 = t * 2;
            float s0 = sm[0][c2] + sm[1][c2] + sm[2][c2] + sm[3][c2];
            float s1 = sm[0][c2 + 1] + sm[1][c2 + 1] + sm[2][c2 + 1] + sm[3][c2 + 1];
            bs[((size_t)b * CIN + c2) * 576 + bh * 24 + bw] = s0;
            bs[((size_t)b * CIN + c2 + 1) * 576 + bh * 24 + bw] = s1;
        }
        __syncthreads();
    }
}

// ---------------------------------------------------------------------------
// poolx stage B: bs[b][c][576] -> xp[b][c][110] (same bin->block mapping as
// the verified pool_x). Block = (c-chunk of 32, b); bs rows staged in LDS.
// ---------------------------------------------------------------------------
__global__ __launch_bounds__(256, 2) void poolx_fin_kernel(
    const float* __restrict__ bs,   // [B][512][576]
    float* __restrict__ xp)         // [B][512][110]
{
    __shared__ float ls[32][576];   // 73.7 KB
    const int c0 = blockIdx.x * 32, b = blockIdx.y;
    const int t = threadIdx.x;

#pragma unroll 1
    for (int r = 0; r < 32; ++r) {
        if (t < 144)
            *(float4*)&ls[r][t * 4] =
                *(const float4*)&bs[((size_t)b * CIN + c0 + r) * 576 + t * 4];
    }
    __syncthreads();

    const int cl = t >> 3, w8 = t & 7;
    const float* row = ls[cl];
    float* xpr = xp + ((size_t)b * CIN + c0 + cl) * KP;
#pragma unroll 1
    for (int k = w8; k < KP; k += 8) {
        float s = 0.f, scl;
        if (k == 0) {
            for (int i = 0; i < 576; ++i) s += row[i];
            scl = 1.0f / 9216.0f;
        } else if (k < 10) {
            int idx = k - 1, bi = idx / 3, bj = idx % 3;
            for (int r = 0; r < 8; ++r)
                for (int cc = 0; cc < 8; ++cc)
                    s += row[(bi * 8 + r) * 24 + bj * 8 + cc];
            scl = 1.0f / 1024.0f;
        } else if (k < 46) {
            int idx = k - 10, bi = idx / 6, bj = idx % 6;
            for (int r = 0; r < 4; ++r)
                for (int cc = 0; cc < 4; ++cc)
                    s += row[(bi * 4 + r) * 24 + bj * 4 + cc];
            scl = 1.0f / 256.0f;
        } else {
            int idx = k - 46, bi = idx / 8, bj = idx % 8;
            for (int r = 0; r < 3; ++r)
                for (int cc = 0; cc < 3; ++cc)
                    s += row[(bi * 3 + r) * 24 + bj * 3 + cc];
            scl = 1.0f / 144.0f;
        }
        xpr[k] = s * scl;
    }
}

// ---------------------------------------------------------------------------
// MFMA GEMM (proven R11 structure): BK=32, 3 buffers, counted vmcnt,
// 48 KB LDS, 3 blocks/CU. slot ^ ((row>>1)&3) swizzle -> <=2-way LDS aliasing.
// ---------------------------------------------------------------------------
template<int KDIM, int MODE>
__global__ __launch_bounds__(256, 3) void gemm_kernel(
    const u16* __restrict__ A,
    const u16* __restrict__ Bw,
    const float* __restrict__ b0, const float* __restrict__ b1,
    const float* __restrict__ resid,
    void* __restrict__ out0_, void* __restrict__ out1_)
{
    __shared__ u16 As[3][128 * 32];
    __shared__ u16 Bs[3][128 * 32];

    constexpr int NSTEP = KDIM / 32;
    constexpr int NWG = 72 * 4 * NB;

    const int id = blockIdx.x;
    const int swz = (id & 7) * (NWG / 8) + (id >> 3);
    const int u = swz % 288;
    const int bz = swz / 288;
    const int by = u & 3;
    const int bx = u >> 2;

    const int t = threadIdx.x;
    const int m0 = bx * 128;
    const int n0 = by * 128;
    const int w = t >> 6, l = t & 63;
    const int wr = w >> 1, wc = w & 1;
    const int g = l >> 4, li = l & 15;

    const u16* Ab = A + (size_t)bz * HWN * KDIM + (size_t)m0 * KDIM;
    const u16* Bb = Bw + (size_t)n0 * KDIM;

    f32x4 zero = {0.f, 0.f, 0.f, 0.f};
    f32x4 acc[4][4];
#pragma unroll
    for (int i = 0; i < 4; ++i)
#pragma unroll
        for (int j = 0; j < 4; ++j) acc[i][j] = zero;

    auto stage = [&](int step) {
        const int buf = step % 3;
#pragma unroll
        for (int j = 0; j < 2; ++j) {
            int c = j * 256 + t;
            int row = c >> 2, slot = c & 3;
            int ss = slot ^ ((row >> 1) & 3);
            gload16(Ab + (size_t)row * KDIM + step * 32 + ss * 8, &As[buf][c * 8]);
        }
#pragma unroll
        for (int j = 0; j < 2; ++j) {
            int c = j * 256 + t;
            int row = c >> 2, slot = c & 3;
            int ss = slot ^ ((row >> 1) & 3);
            gload16(Bb + (size_t)row * KDIM + step * 32 + ss * 8, &Bs[buf][c * 8]);
        }
    };

    stage(0);
    stage(1);

#pragma unroll 1
    for (int s = 0; s < NSTEP; ++s) {
        if (s + 2 < NSTEP) {
            stage(s + 2);
            asm volatile("s_waitcnt vmcnt(8)" ::: "memory");
        } else if (s + 1 < NSTEP) {
            asm volatile("s_waitcnt vmcnt(4)" ::: "memory");
        } else {
            asm volatile("s_waitcnt vmcnt(0)" ::: "memory");
        }
        __builtin_amdgcn_s_barrier();
        __builtin_amdgcn_sched_barrier(0);

        const int cb = s % 3;
        bf16x8 af[4], bv[4];
#pragma unroll
        for (int mi = 0; mi < 4; ++mi) {
            int r = wr * 64 + mi * 16 + li;
            int sl = g ^ ((r >> 1) & 3);
            af[mi] = *(const bf16x8*)&As[cb][r * 32 + sl * 8];
        }
#pragma unroll
        for (int ni = 0; ni < 4; ++ni) {
            int r = wc * 64 + ni * 16 + li;
            int sl = g ^ ((r >> 1) & 3);
            bv[ni] = *(const bf16x8*)&Bs[cb][r * 32 + sl * 8];
        }
#pragma unroll
        for (int mi = 0; mi < 4; ++mi)
#pragma unroll
            for (int ni = 0; ni < 4; ++ni)
                acc[mi][ni] = __builtin_amdgcn_mfma_f32_16x16x32_bf16(
                    af[mi], bv[ni], acc[mi][ni], 0, 0, 0);

        __builtin_amdgcn_s_barrier();
    }

#pragma unroll
    for (int ni = 0; ni < 4; ++ni) {
        int n = n0 + wc * 64 + ni * 16 + li;
        if constexpr (MODE == 0) {
            float bias = (n < 256) ? b0[n] : b1[n - 256];
            u16* dst = (u16*)((n < 256) ? out0_ : out1_) + ((size_t)bz * 256 + (n & 255)) * HWN;
#pragma unroll
            for (int mi = 0; mi < 4; ++mi) {
                int m = m0 + wr * 64 + mi * 16 + (g << 2);
                f32x4 v = acc[mi][ni];
                float e0 = fmaxf(v.x + bias, 0.f), e1 = fmaxf(v.y + bias, 0.f);
                float e2 = fmaxf(v.z + bias, 0.f), e3 = fmaxf(v.w + bias, 0.f);
                uint2 pk = {bf16_pack(e0, e1), bf16_pack(e2, e3)};
                *(uint2*)(dst + m) = pk;
            }
        } else {
            float bias = b0[n];
            float* dst = (float*)out0_ + ((size_t)bz * 512 + n) * HWN;
            const float* res = resid + ((size_t)bz * 512 + n) * HWN;
#pragma unroll
            for (int mi = 0; mi < 4; ++mi) {
                int m = m0 + wr * 64 + mi * 16 + (g << 2);
                f32x4 v = acc[mi][ni];
                float4 rx = *(const float4*)(res + m);
                float4 o = {v.x + bias + rx.x, v.y + bias + rx.y,
                            v.z + bias + rx.z, v.w + bias + rx.w};
                *(float4*)(dst + m) = o;
            }
        }
    }
}

// ---------------------------------------------------------------------------
// SPP pooling, bf16 input (theta) -> tpT [B][128][256] bf16 transposed, padded
// ---------------------------------------------------------------------------
__global__ __launch_bounds__(256) void pool_t_kernel(
    const u16* __restrict__ in, u16* __restrict__ outT)
{
    __shared__ float ps[576];
    const int plane = blockIdx.x;
    const int b = plane >> 8, c = plane & 255;
    const u16* p = in + (size_t)plane * HWN;
    const int t = threadIdx.x;

    for (int i = t; i < 576; i += 256) {
        int bh = i / 24, bw = i % 24;
        float s = 0.f;
#pragma unroll
        for (int r = 0; r < 4; ++r) {
            ushort4 v = *(const ushort4*)&p[(bh * 4 + r) * 96 + bw * 4];
            s += b2f(v.x) + b2f(v.y) + b2f(v.z) + b2f(v.w);
        }
        ps[i] = s;
    }
    __syncthreads();

    if (t < 128) {
        float s = 0.f;
        if (t == 0) {
            for (int i = 0; i < 576; ++i) s += ps[i];
            s *= (1.0f / 9216.0f);
        } else if (t < 10) {
            int idx = t - 1, bi = idx / 3, bj = idx % 3;
            for (int r = 0; r < 8; ++r)
                for (int cc = 0; cc < 8; ++cc)
                    s += ps[(bi * 8 + r) * 24 + bj * 8 + cc];
            s *= (1.0f / 1024.0f);
        } else if (t < 46) {
            int idx = t - 10, bi = idx / 6, bj = idx % 6;
            for (int r = 0; r < 4; ++r)
                for (int cc = 0; cc < 4; ++cc)
                    s += ps[(bi * 4 + r) * 24 + bj * 4 + cc];
            s *= (1.0f / 256.0f);
        } else if (t < KP) {
            int idx = t - 46, bi = idx / 8, bj = idx % 8;
            for (int r = 0; r < 3; ++r)
                for (int cc = 0; cc < 3; ++cc)
                    s += ps[(bi * 3 + r) * 24 + bj * 3 + cc];
            s *= (1.0f / 144.0f);
        } else {
            s = 0.f;
        }
        outT[((size_t)b * 128 + t) * 256 + c] = (u16)bf16_1(s);
    }
}

// ---------------------------------------------------------------------------
// gamma_p k-minor, L2-efficient: block = 8 k values x 256 o.
// ---------------------------------------------------------------------------
__global__ __launch_bounds__(256) void gammap_kernel(
    const float* __restrict__ xp,   // [B][512][110]
    const float* __restrict__ gw,   // [256][512]
    const float* __restrict__ gb,   // [256]
    u16* __restrict__ gp)           // [B][256][128]
{
    __shared__ float xc[8][512];
    const int kb = blockIdx.x * 8, b = blockIdx.y;
    const int t = threadIdx.x;

#pragma unroll
    for (int j = 0; j < 16; ++j) {
        int idx = j * 256 + t;
        int kk = idx >> 9, c = idx & 511;
        int k = kb + kk;
        xc[kk][c] = (k < KP) ? xp[((size_t)b * CIN + c) * KP + k] : 0.f;
    }
    __syncthreads();

    float bias = gb[t];
    float acc[8];
#pragma unroll
    for (int kk = 0; kk < 8; ++kk) acc[kk] = bias;

    const float* wrow = gw + (size_t)t * CIN;
#pragma unroll 2
    for (int c = 0; c < CIN; c += 4) {
        float4 wv = *(const float4*)&wrow[c];
#pragma unroll
        for (int kk = 0; kk < 8; ++kk) {
            acc[kk] = fmaf(wv.x, xc[kk][c], acc[kk]);
            acc[kk] = fmaf(wv.y, xc[kk][c + 1], acc[kk]);
            acc[kk] = fmaf(wv.z, xc[kk][c + 2], acc[kk]);
            acc[kk] = fmaf(wv.w, xc[kk][c + 3], acc[kk]);
        }
    }

    ushort4 o0, o1;
    o0.x = (u16)bf16_1(acc[0]); o0.y = (u16)bf16_1(acc[1]);
    o0.z = (u16)bf16_1(acc[2]); o0.w = (u16)bf16_1(acc[3]);
    o1.x = (u16)bf16_1(acc[4]); o1.y = (u16)bf16_1(acc[5]);
    o1.z = (u16)bf16_1(acc[6]); o1.w = (u16)bf16_1(acc[7]);
    u16* dst = gp + ((size_t)b * 256 + t) * 128 + kb;
    *(ushort4*)(dst) = o0;
    *(ushort4*)(dst + 4) = o1;
}

// ---------------------------------------------------------------------------
// MFMA attention, 64-ci blocks (R10 structure).
// ---------------------------------------------------------------------------
__global__ __launch_bounds__(256, 4) void attn_kernel(
    const u16* __restrict__ phi,   // [B][256][9216] bf16
    const u16* __restrict__ tpT,   // [B][128][256] bf16
    const u16* __restrict__ gp,    // [B][256][128] bf16
    u16* __restrict__ y2T)         // [B][9216 hw'][256 ci] bf16
{
    __shared__ __align__(16) char smem[40960];
    u16* As = (u16*)smem;
    u16* Bs = (u16*)(smem + 8192);
    char* Pb = smem + 24576;
    u16* Gs = (u16*)smem;

    const int t = threadIdx.x;
    const int w = t >> 6, l = t & 63;
    const int g = l >> 4, li = l & 15;
    const int b = blockIdx.y;
    const int rr = blockIdx.x >> 2;
    const int ci0 = (blockIdx.x & 3) << 6;

    const u16* phib = phi + (size_t)b * (OIN * HWN);
    const u16* tpb  = tpT + (size_t)b * (128 * 256);
    const u16* gpb  = gp  + (size_t)b * (256 * 128);

    const int srow = t >> 3;
    const int su = t & 7;

    f32x4 zero = {0.f, 0.f, 0.f, 0.f};
    f32x4 acc[8];
#pragma unroll
    for (int j = 0; j < 8; ++j) acc[j] = zero;

    for (int kt = 0; kt < 256; kt += 64) {
#pragma unroll
        for (int cc = 0; cc < 2; ++cc) {
            int row = cc * 32 + srow;
            int ss = su ^ (row & 7);
            gload16(phib + (size_t)(ci0 + row) * HWN + rr * 256 + kt + ss * 8,
                    &As[(row * 8 + su) * 8]);
        }
#pragma unroll
        for (int cc = 0; cc < 4; ++cc) {
            int row = cc * 32 + srow;
            int ss = su ^ (row & 7);
            gload16(tpb + (size_t)row * 256 + kt + ss * 8,
                    &Bs[(row * 8 + su) * 8]);
        }
        __syncthreads();

#pragma unroll
        for (int h = 0; h < 2; ++h) {
            int r = w * 16 + li;
            bf16x8 af = *(const bf16x8*)&As[r * 64 + (((h * 4 + g) ^ (r & 7)) << 3)];
            bf16x8 bfr[8];
#pragma unroll
            for (int ni = 0; ni < 8; ++ni) {
                int rb = ni * 16 + li;
                bfr[ni] = *(const bf16x8*)&Bs[rb * 64 + (((h * 4 + g) ^ (rb & 7)) << 3)];
            }
#pragma unroll
            for (int ni = 0; ni < 8; ++ni)
                acc[ni] = __builtin_amdgcn_mfma_f32_16x16x32_bf16(
                    af, bfr[ni], acc[ni], 0, 0, 0);
        }
        __syncthreads();
    }

    bool vm[8];
#pragma unroll
    for (int ni = 0; ni < 8; ++ni) vm[ni] = (ni * 16 + li) < KP;

#pragma unroll
    for (int r = 0; r < 4; ++r) {
        float mx = -1e30f;
#pragma unroll
        for (int ni = 0; ni < 8; ++ni)
            if (vm[ni]) mx = fmaxf(mx, acc[ni][r] * SCL);
        mx = fmaxf(mx, __shfl_xor(mx, 1));
        mx = fmaxf(mx, __shfl_xor(mx, 2));
        mx = fmaxf(mx, __shfl_xor(mx, 4));
        mx = fmaxf(mx, __shfl_xor(mx, 8));
        float s = 0.f;
#pragma unroll
        for (int ni = 0; ni < 8; ++ni) {
            float e = vm[ni] ? __expf(acc[ni][r] * SCL - mx) : 0.f;
            acc[ni][r] = e;
            s += e;
        }
        s += __shfl_xor(s, 1);
        s += __shfl_xor(s, 2);
        s += __shfl_xor(s, 4);
        s += __shfl_xor(s, 8);
        float inv = 1.0f / s;
#pragma unroll
        for (int ni = 0; ni < 8; ++ni) acc[ni][r] *= inv;
    }
#pragma unroll
    for (int ni = 0; ni < 8; ++ni)
#pragma unroll
        for (int r = 0; r < 4; ++r) {
            int row = w * 16 + g * 4 + r;
            int col = ni * 16 + li;
            *(short*)(Pb + row * 256 + (((col >> 3) ^ (row & 7)) << 4) + ((col & 7) << 1)) =
                (short)bf16_1(acc[ni][r]);
        }

    f32x4 acc2[16];
#pragma unroll
    for (int j = 0; j < 16; ++j) acc2[j] = zero;

#pragma unroll 1
    for (int ch = 0; ch < 4; ++ch) {
#pragma unroll
        for (int j = 0; j < 4; ++j) {
            int row = j * 64 + (t >> 2);
            int slot = t & 3;
            int ss = slot ^ (row & 3);
            gload16(gpb + (size_t)row * 128 + ch * 32 + ss * 8,
                    &Gs[(j * 256 + t) * 8]);
        }
        __syncthreads();

        int prow = w * 16 + li;
        bf16x8 a2 = *(const bf16x8*)(Pb + prow * 256 + (((ch * 4 + g) ^ (prow & 7)) << 4));
#pragma unroll
        for (int cf = 0; cf < 16; ++cf) {
            int crow = cf * 16 + li;
            bf16x8 bv = *(const bf16x8*)((const char*)Gs + crow * 64 + ((g ^ (crow & 3)) << 4));
            acc2[cf] = __builtin_amdgcn_mfma_f32_16x16x32_bf16(a2, bv, acc2[cf], 0, 0, 0);
        }
        __syncthreads();
    }

#pragma unroll
    for (int cf = 0; cf < 16; ++cf) {
        int c = cf * 16 + li;
        int cib = w * 16 + g * 4;
        int e0 = c * 64 + (cib ^ ((li & 7) << 3));
        unsigned d0 = bf16_pack(acc2[cf][0], acc2[cf][1]);
        unsigned d1 = bf16_pack(acc2[cf][2], acc2[cf][3]);
        *(unsigned*)(smem + (size_t)e0 * 2) = d0;
        *(unsigned*)(smem + (size_t)e0 * 2 + 4) = d1;
    }

    __syncthreads();

    {
        int c = t;
        u16* dst = y2T + ((size_t)b * HWN + rr * 256 + c) * 256 + ci0;
#pragma unroll
        for (int j = 0; j < 8; ++j) {
            uint4 v = *(const uint4*)(smem + c * 128 + ((j ^ (c & 7)) << 4));
            *(uint4*)(dst + j * 8) = v;
        }
    }
}

extern "C" void kernel_launch(void* const* d_in, const int* in_sizes, int n_in,
                              void* d_out, int out_size, void* d_ws, size_t ws_size,
                              hipStream_t stream)
{
    const float* x       = (const float*)d_in[0];
    const float* phi_w   = (const float*)d_in[1];
    const float* phi_b   = (const float*)d_in[2];
    const float* theta_w = (const float*)d_in[3];
    const float* theta_b = (const float*)d_in[4];
    const float* gamma_w = (const float*)d_in[5];
    const float* gamma_b = (const float*)d_in[6];
    const float* W_w     = (const float*)d_in[7];
    const float* W_b     = (const float*)d_in[8];
    float* out = (float*)d_out;

    char* p = (char*)d_ws;
    u16* xT     = (u16*)p;  p += (size_t)NB * HWN * CIN * 2;   // 75.5 MB
    u16* phi_bf = (u16*)p;  p += (size_t)NB * OIN * HWN * 2;   // 37.7 MB
    u16* th_y2  = (u16*)p;  p += (size_t)NB * OIN * HWN * 2;   // 37.7 MB (theta, then y2T)
    float* xp   = (float*)p; p += (size_t)NB * CIN * KP * 4;
    u16* tpT    = (u16*)p;  p += (size_t)NB * 128 * 256 * 2;
    u16* gp     = (u16*)p;  p += (size_t)NB * 256 * 128 * 2;
    u16* Wcat   = (u16*)p;  p += 512 * 512 * 2;
    u16* Wwb    = (u16*)p;  p += 512 * 256 * 2;
    float* bs   = (float*)p; p += (size_t)NB * CIN * 576 * 4;  // 9.4 MB

    castw_kernel<<<1536, 256, 0, stream>>>(phi_w, theta_w, W_w, Wcat, Wwb);
    castx_kernel<<<dim3(144, 8, NB), 256, 0, stream>>>(x, xT);
    // pool from xT (bf16, L3-hot): stage A block-sums, stage B bin-combine
    poolx_bs_kernel<<<dim3(24, NB), 256, 0, stream>>>(xT, bs);
    poolx_fin_kernel<<<dim3(16, NB), 256, 0, stream>>>(bs, xp);
    gemm_kernel<512, 0><<<dim3(72 * 4 * NB), 256, 0, stream>>>(
        xT, Wcat, phi_b, theta_b, nullptr, phi_bf, th_y2);
    pool_t_kernel<<<dim3(NB * OIN), 256, 0, stream>>>(th_y2, tpT);
    gammap_kernel<<<dim3(16, NB), 256, 0, stream>>>(xp, gamma_w, gamma_b, gp);
    attn_kernel<<<dim3(144, NB), 256, 0, stream>>>(phi_bf, tpT, gp, th_y2);
    gemm_kernel<256, 1><<<dim3(72 * 4 * NB), 256, 0, stream>>>(
        th_y2, Wwb, W_b, nullptr, x, out, nullptr);
}

// Round 16
// 315.826 us; speedup vs baseline: 1.0152x; 1.0152x over previous
//
#include <hip/hip_runtime.h>

#define NB 8
#define CIN 512
#define OIN 256
#define HWN 9216
#define KP 110
#define SCL 0.10206207261596577f  // 9216^(-0.25)

typedef __attribute__((ext_vector_type(8))) short bf16x8;
typedef __attribute__((ext_vector_type(4))) float f32x4;
typedef unsigned short u16;

__device__ inline unsigned bf16_1(float a) {
    unsigned u = __builtin_bit_cast(unsigned, a);
    return (u + 0x7fffu + ((u >> 16) & 1u)) >> 16;
}
__device__ inline unsigned bf16_pack(float a, float b) {
    return bf16_1(a) | (bf16_1(b) << 16);
}
__device__ inline float b2f(u16 u) {
    return __builtin_bit_cast(float, ((unsigned)u) << 16);
}

__device__ __forceinline__ void gload16(const u16* g, u16* l) {
    __builtin_amdgcn_global_load_lds(
        (const __attribute__((address_space(1))) unsigned int*)g,
        (__attribute__((address_space(3))) unsigned int*)l, 16, 0, 0);
}

// ---------------------------------------------------------------------------
// Weight cast: phi_w+theta_w -> Wcat bf16 [512][512]; W_w -> Wwb bf16 [512][256]
// ---------------------------------------------------------------------------
__global__ __launch_bounds__(256) void castw_kernel(
    const float* __restrict__ phi_w, const float* __restrict__ theta_w,
    const float* __restrict__ Ww,
    u16* __restrict__ Wcat, u16* __restrict__ Wwb)
{
    int i = blockIdx.x * 256 + threadIdx.x;
    if (i < 262144) {
        float v = (i < 131072) ? phi_w[i] : theta_w[i - 131072];
        Wcat[i] = (u16)bf16_1(v);
    } else {
        int j = i - 262144;
        Wwb[j] = (u16)bf16_1(Ww[j]);
    }
}

// ---------------------------------------------------------------------------
// castx: x fp32 [b][512 c][9216 hw] -> xT bf16 [b][9216 hw][512 c]
// ---------------------------------------------------------------------------
__global__ __launch_bounds__(256) void castx_kernel(
    const float* __restrict__ x, u16* __restrict__ xT)
{
    const int t = threadIdx.x;
    const int tx = t & 15, ty = t >> 4;
    const int b = blockIdx.z;
    const int c0 = blockIdx.y * 64;
    const int hw0 = blockIdx.x * 64;

    const float* xb = x + ((size_t)b * CIN + c0 + ty * 4) * HWN + hw0 + tx * 4;
    float4 v[4];
#pragma unroll
    for (int q = 0; q < 4; ++q)
        v[q] = *(const float4*)(xb + (size_t)q * HWN);

    u16* dst = xT + ((size_t)b * HWN + hw0 + tx * 4) * CIN + c0 + ty * 4;
    const float* f = (const float*)v;
#pragma unroll
    for (int p = 0; p < 4; ++p) {
        uint2 o = {bf16_pack(f[0 * 4 + p], f[1 * 4 + p]),
                   bf16_pack(f[2 * 4 + p], f[3 * 4 + p])};
        *(uint2*)(dst + (size_t)p * CIN) = o;
    }
}

// ---------------------------------------------------------------------------
// poolx stage A (R14 fix: full parallelism): one block per (4x4 block, b).
// Grid (576, NB) = 4608 blocks. Each block reads 16 hw-rows x 512 c bf16
// (16 KB, 1KB-contiguous per wave-read), LDS cross-wave reduce, writes 512
// block-sums. bs writes are 4B scattered but 16 blocks share each 64B line
// (L2-merged; bs total is 9.4 MB).
// ---------------------------------------------------------------------------
__global__ __launch_bounds__(256) void poolx_bs_kernel(
    const u16* __restrict__ xT,   // [B][9216][512]
    float* __restrict__ bs)       // [B][512][576]
{
    __shared__ float sm[4][512];
    const int blk = blockIdx.x;            // 0..575 = bh*24+bw
    const int b = blockIdx.y;
    const int bh = blk / 24, bw = blk % 24;
    const int t = threadIdx.x;
    const int g = t >> 6;                  // h within the 4-row group
    const int co = (t & 63) * 8;           // c octet

    float a[8] = {0.f, 0.f, 0.f, 0.f, 0.f, 0.f, 0.f, 0.f};
    const int hwbase = (bh * 4 + g) * 96 + bw * 4;
    const u16* base = xT + ((size_t)b * HWN + hwbase) * CIN + co;
#pragma unroll
    for (int wI = 0; wI < 4; ++wI) {
        uint4 v = *(const uint4*)(base + (size_t)wI * CIN);
        a[0] += b2f((u16)v.x); a[1] += b2f((u16)(v.x >> 16));
        a[2] += b2f((u16)v.y); a[3] += b2f((u16)(v.y >> 16));
        a[4] += b2f((u16)v.z); a[5] += b2f((u16)(v.z >> 16));
        a[6] += b2f((u16)v.w); a[7] += b2f((u16)(v.w >> 16));
    }
#pragma unroll
    for (int j = 0; j < 8; ++j) sm[g][co + j] = a[j];
    __syncthreads();
    {
        int c2 = t * 2;
        float s0 = sm[0][c2] + sm[1][c2] + sm[2][c2] + sm[3][c2];
        float s1 = sm[0][c2 + 1] + sm[1][c2 + 1] + sm[2][c2 + 1] + sm[3][c2 + 1];
        bs[((size_t)b * CIN + c2) * 576 + blk] = s0;
        bs[((size_t)b * CIN + c2 + 1) * 576 + blk] = s1;
    }
}

// ---------------------------------------------------------------------------
// poolx stage B: bs[b][c][576] -> xp[b][c][110] (verified bin->block map).
// ---------------------------------------------------------------------------
__global__ __launch_bounds__(256, 2) void poolx_fin_kernel(
    const float* __restrict__ bs,   // [B][512][576]
    float* __restrict__ xp)         // [B][512][110]
{
    __shared__ float ls[32][576];   // 73.7 KB
    const int c0 = blockIdx.x * 32, b = blockIdx.y;
    const int t = threadIdx.x;

#pragma unroll 1
    for (int r = 0; r < 32; ++r) {
        if (t < 144)
            *(float4*)&ls[r][t * 4] =
                *(const float4*)&bs[((size_t)b * CIN + c0 + r) * 576 + t * 4];
    }
    __syncthreads();

    const int cl = t >> 3, w8 = t & 7;
    const float* row = ls[cl];
    float* xpr = xp + ((size_t)b * CIN + c0 + cl) * KP;
#pragma unroll 1
    for (int k = w8; k < KP; k += 8) {
        float s = 0.f, scl;
        if (k == 0) {
            for (int i = 0; i < 576; ++i) s += row[i];
            scl = 1.0f / 9216.0f;
        } else if (k < 10) {
            int idx = k - 1, bi = idx / 3, bj = idx % 3;
            for (int r = 0; r < 8; ++r)
                for (int cc = 0; cc < 8; ++cc)
                    s += row[(bi * 8 + r) * 24 + bj * 8 + cc];
            scl = 1.0f / 1024.0f;
        } else if (k < 46) {
            int idx = k - 10, bi = idx / 6, bj = idx % 6;
            for (int r = 0; r < 4; ++r)
                for (int cc = 0; cc < 4; ++cc)
                    s += row[(bi * 4 + r) * 24 + bj * 4 + cc];
            scl = 1.0f / 256.0f;
        } else {
            int idx = k - 46, bi = idx / 8, bj = idx % 8;
            for (int r = 0; r < 3; ++r)
                for (int cc = 0; cc < 3; ++cc)
                    s += row[(bi * 3 + r) * 24 + bj * 3 + cc];
            scl = 1.0f / 144.0f;
        }
        xpr[k] = s * scl;
    }
}

// ---------------------------------------------------------------------------
// MFMA GEMM (proven R11 structure): BK=32, 3 buffers, counted vmcnt,
// 48 KB LDS, 3 blocks/CU. slot ^ ((row>>1)&3) swizzle -> <=2-way LDS aliasing.
// ---------------------------------------------------------------------------
template<int KDIM, int MODE>
__global__ __launch_bounds__(256, 3) void gemm_kernel(
    const u16* __restrict__ A,
    const u16* __restrict__ Bw,
    const float* __restrict__ b0, const float* __restrict__ b1,
    const float* __restrict__ resid,
    void* __restrict__ out0_, void* __restrict__ out1_)
{
    __shared__ u16 As[3][128 * 32];
    __shared__ u16 Bs[3][128 * 32];

    constexpr int NSTEP = KDIM / 32;
    constexpr int NWG = 72 * 4 * NB;

    const int id = blockIdx.x;
    const int swz = (id & 7) * (NWG / 8) + (id >> 3);
    const int u = swz % 288;
    const int bz = swz / 288;
    const int by = u & 3;
    const int bx = u >> 2;

    const int t = threadIdx.x;
    const int m0 = bx * 128;
    const int n0 = by * 128;
    const int w = t >> 6, l = t & 63;
    const int wr = w >> 1, wc = w & 1;
    const int g = l >> 4, li = l & 15;

    const u16* Ab = A + (size_t)bz * HWN * KDIM + (size_t)m0 * KDIM;
    const u16* Bb = Bw + (size_t)n0 * KDIM;

    f32x4 zero = {0.f, 0.f, 0.f, 0.f};
    f32x4 acc[4][4];
#pragma unroll
    for (int i = 0; i < 4; ++i)
#pragma unroll
        for (int j = 0; j < 4; ++j) acc[i][j] = zero;

    auto stage = [&](int step) {
        const int buf = step % 3;
#pragma unroll
        for (int j = 0; j < 2; ++j) {
            int c = j * 256 + t;
            int row = c >> 2, slot = c & 3;
            int ss = slot ^ ((row >> 1) & 3);
            gload16(Ab + (size_t)row * KDIM + step * 32 + ss * 8, &As[buf][c * 8]);
        }
#pragma unroll
        for (int j = 0; j < 2; ++j) {
            int c = j * 256 + t;
            int row = c >> 2, slot = c & 3;
            int ss = slot ^ ((row >> 1) & 3);
            gload16(Bb + (size_t)row * KDIM + step * 32 + ss * 8, &Bs[buf][c * 8]);
        }
    };

    stage(0);
    stage(1);

#pragma unroll 1
    for (int s = 0; s < NSTEP; ++s) {
        if (s + 2 < NSTEP) {
            stage(s + 2);
            asm volatile("s_waitcnt vmcnt(8)" ::: "memory");
        } else if (s + 1 < NSTEP) {
            asm volatile("s_waitcnt vmcnt(4)" ::: "memory");
        } else {
            asm volatile("s_waitcnt vmcnt(0)" ::: "memory");
        }
        __builtin_amdgcn_s_barrier();
        __builtin_amdgcn_sched_barrier(0);

        const int cb = s % 3;
        bf16x8 af[4], bv[4];
#pragma unroll
        for (int mi = 0; mi < 4; ++mi) {
            int r = wr * 64 + mi * 16 + li;
            int sl = g ^ ((r >> 1) & 3);
            af[mi] = *(const bf16x8*)&As[cb][r * 32 + sl * 8];
        }
#pragma unroll
        for (int ni = 0; ni < 4; ++ni) {
            int r = wc * 64 + ni * 16 + li;
            int sl = g ^ ((r >> 1) & 3);
            bv[ni] = *(const bf16x8*)&Bs[cb][r * 32 + sl * 8];
        }
#pragma unroll
        for (int mi = 0; mi < 4; ++mi)
#pragma unroll
            for (int ni = 0; ni < 4; ++ni)
                acc[mi][ni] = __builtin_amdgcn_mfma_f32_16x16x32_bf16(
                    af[mi], bv[ni], acc[mi][ni], 0, 0, 0);

        __builtin_amdgcn_s_barrier();
    }

#pragma unroll
    for (int ni = 0; ni < 4; ++ni) {
        int n = n0 + wc * 64 + ni * 16 + li;
        if constexpr (MODE == 0) {
            float bias = (n < 256) ? b0[n] : b1[n - 256];
            u16* dst = (u16*)((n < 256) ? out0_ : out1_) + ((size_t)bz * 256 + (n & 255)) * HWN;
#pragma unroll
            for (int mi = 0; mi < 4; ++mi) {
                int m = m0 + wr * 64 + mi * 16 + (g << 2);
                f32x4 v = acc[mi][ni];
                float e0 = fmaxf(v.x + bias, 0.f), e1 = fmaxf(v.y + bias, 0.f);
                float e2 = fmaxf(v.z + bias, 0.f), e3 = fmaxf(v.w + bias, 0.f);
                uint2 pk = {bf16_pack(e0, e1), bf16_pack(e2, e3)};
                *(uint2*)(dst + m) = pk;
            }
        } else {
            float bias = b0[n];
            float* dst = (float*)out0_ + ((size_t)bz * 512 + n) * HWN;
            const float* res = resid + ((size_t)bz * 512 + n) * HWN;
#pragma unroll
            for (int mi = 0; mi < 4; ++mi) {
                int m = m0 + wr * 64 + mi * 16 + (g << 2);
                f32x4 v = acc[mi][ni];
                float4 rx = *(const float4*)(res + m);
                float4 o = {v.x + bias + rx.x, v.y + bias + rx.y,
                            v.z + bias + rx.z, v.w + bias + rx.w};
                *(float4*)(dst + m) = o;
            }
        }
    }
}

// ---------------------------------------------------------------------------
// SPP pooling, bf16 input (theta) -> tpT [B][128][256] bf16 transposed, padded
// ---------------------------------------------------------------------------
__global__ __launch_bounds__(256) void pool_t_kernel(
    const u16* __restrict__ in, u16* __restrict__ outT)
{
    __shared__ float ps[576];
    const int plane = blockIdx.x;
    const int b = plane >> 8, c = plane & 255;
    const u16* p = in + (size_t)plane * HWN;
    const int t = threadIdx.x;

    for (int i = t; i < 576; i += 256) {
        int bh = i / 24, bw = i % 24;
        float s = 0.f;
#pragma unroll
        for (int r = 0; r < 4; ++r) {
            ushort4 v = *(const ushort4*)&p[(bh * 4 + r) * 96 + bw * 4];
            s += b2f(v.x) + b2f(v.y) + b2f(v.z) + b2f(v.w);
        }
        ps[i] = s;
    }
    __syncthreads();

    if (t < 128) {
        float s = 0.f;
        if (t == 0) {
            for (int i = 0; i < 576; ++i) s += ps[i];
            s *= (1.0f / 9216.0f);
        } else if (t < 10) {
            int idx = t - 1, bi = idx / 3, bj = idx % 3;
            for (int r = 0; r < 8; ++r)
                for (int cc = 0; cc < 8; ++cc)
                    s += ps[(bi * 8 + r) * 24 + bj * 8 + cc];
            s *= (1.0f / 1024.0f);
        } else if (t < 46) {
            int idx = t - 10, bi = idx / 6, bj = idx % 6;
            for (int r = 0; r < 4; ++r)
                for (int cc = 0; cc < 4; ++cc)
                    s += ps[(bi * 4 + r) * 24 + bj * 4 + cc];
            s *= (1.0f / 256.0f);
        } else if (t < KP) {
            int idx = t - 46, bi = idx / 8, bj = idx % 8;
            for (int r = 0; r < 3; ++r)
                for (int cc = 0; cc < 3; ++cc)
                    s += ps[(bi * 3 + r) * 24 + bj * 3 + cc];
            s *= (1.0f / 144.0f);
        } else {
            s = 0.f;
        }
        outT[((size_t)b * 128 + t) * 256 + c] = (u16)bf16_1(s);
    }
}

// ---------------------------------------------------------------------------
// gamma_p k-minor, L2-efficient: block = 8 k values x 256 o.
// ---------------------------------------------------------------------------
__global__ __launch_bounds__(256) void gammap_kernel(
    const float* __restrict__ xp,   // [B][512][110]
    const float* __restrict__ gw,   // [256][512]
    const float* __restrict__ gb,   // [256]
    u16* __restrict__ gp)           // [B][256][128]
{
    __shared__ float xc[8][512];
    const int kb = blockIdx.x * 8, b = blockIdx.y;
    const int t = threadIdx.x;

#pragma unroll
    for (int j = 0; j < 16; ++j) {
        int idx = j * 256 + t;
        int kk = idx >> 9, c = idx & 511;
        int k = kb + kk;
        xc[kk][c] = (k < KP) ? xp[((size_t)b * CIN + c) * KP + k] : 0.f;
    }
    __syncthreads();

    float bias = gb[t];
    float acc[8];
#pragma unroll
    for (int kk = 0; kk < 8; ++kk) acc[kk] = bias;

    const float* wrow = gw + (size_t)t * CIN;
#pragma unroll 2
    for (int c = 0; c < CIN; c += 4) {
        float4 wv = *(const float4*)&wrow[c];
#pragma unroll
        for (int kk = 0; kk < 8; ++kk) {
            acc[kk] = fmaf(wv.x, xc[kk][c], acc[kk]);
            acc[kk] = fmaf(wv.y, xc[kk][c + 1], acc[kk]);
            acc[kk] = fmaf(wv.z, xc[kk][c + 2], acc[kk]);
            acc[kk] = fmaf(wv.w, xc[kk][c + 3], acc[kk]);
        }
    }

    ushort4 o0, o1;
    o0.x = (u16)bf16_1(acc[0]); o0.y = (u16)bf16_1(acc[1]);
    o0.z = (u16)bf16_1(acc[2]); o0.w = (u16)bf16_1(acc[3]);
    o1.x = (u16)bf16_1(acc[4]); o1.y = (u16)bf16_1(acc[5]);
    o1.z = (u16)bf16_1(acc[6]); o1.w = (u16)bf16_1(acc[7]);
    u16* dst = gp + ((size_t)b * 256 + t) * 128 + kb;
    *(ushort4*)(dst) = o0;
    *(ushort4*)(dst + 4) = o1;
}

// ---------------------------------------------------------------------------
// MFMA attention, 64-ci blocks (R10 structure).
// ---------------------------------------------------------------------------
__global__ __launch_bounds__(256, 4) void attn_kernel(
    const u16* __restrict__ phi,   // [B][256][9216] bf16
    const u16* __restrict__ tpT,   // [B][128][256] bf16
    const u16* __restrict__ gp,    // [B][256][128] bf16
    u16* __restrict__ y2T)         // [B][9216 hw'][256 ci] bf16
{
    __shared__ __align__(16) char smem[40960];
    u16* As = (u16*)smem;
    u16* Bs = (u16*)(smem + 8192);
    char* Pb = smem + 24576;
    u16* Gs = (u16*)smem;

    const int t = threadIdx.x;
    const int w = t >> 6, l = t & 63;
    const int g = l >> 4, li = l & 15;
    const int b = blockIdx.y;
    const int rr = blockIdx.x >> 2;
    const int ci0 = (blockIdx.x & 3) << 6;

    const u16* phib = phi + (size_t)b * (OIN * HWN);
    const u16* tpb  = tpT + (size_t)b * (128 * 256);
    const u16* gpb  = gp  + (size_t)b * (256 * 128);

    const int srow = t >> 3;
    const int su = t & 7;

    f32x4 zero = {0.f, 0.f, 0.f, 0.f};
    f32x4 acc[8];
#pragma unroll
    for (int j = 0; j < 8; ++j) acc[j] = zero;

    for (int kt = 0; kt < 256; kt += 64) {
#pragma unroll
        for (int cc = 0; cc < 2; ++cc) {
            int row = cc * 32 + srow;
            int ss = su ^ (row & 7);
            gload16(phib + (size_t)(ci0 + row) * HWN + rr * 256 + kt + ss * 8,
                    &As[(row * 8 + su) * 8]);
        }
#pragma unroll
        for (int cc = 0; cc < 4; ++cc) {
            int row = cc * 32 + srow;
            int ss = su ^ (row & 7);
            gload16(tpb + (size_t)row * 256 + kt + ss * 8,
                    &Bs[(row * 8 + su) * 8]);
        }
        __syncthreads();

#pragma unroll
        for (int h = 0; h < 2; ++h) {
            int r = w * 16 + li;
            bf16x8 af = *(const bf16x8*)&As[r * 64 + (((h * 4 + g) ^ (r & 7)) << 3)];
            bf16x8 bfr[8];
#pragma unroll
            for (int ni = 0; ni < 8; ++ni) {
                int rb = ni * 16 + li;
                bfr[ni] = *(const bf16x8*)&Bs[rb * 64 + (((h * 4 + g) ^ (rb & 7)) << 3)];
            }
#pragma unroll
            for (int ni = 0; ni < 8; ++ni)
                acc[ni] = __builtin_amdgcn_mfma_f32_16x16x32_bf16(
                    af, bfr[ni], acc[ni], 0, 0, 0);
        }
        __syncthreads();
    }

    bool vm[8];
#pragma unroll
    for (int ni = 0; ni < 8; ++ni) vm[ni] = (ni * 16 + li) < KP;

#pragma unroll
    for (int r = 0; r < 4; ++r) {
        float mx = -1e30f;
#pragma unroll
        for (int ni = 0; ni < 8; ++ni)
            if (vm[ni]) mx = fmaxf(mx, acc[ni][r] * SCL);
        mx = fmaxf(mx, __shfl_xor(mx, 1));
        mx = fmaxf(mx, __shfl_xor(mx, 2));
        mx = fmaxf(mx, __shfl_xor(mx, 4));
        mx = fmaxf(mx, __shfl_xor(mx, 8));
        float s = 0.f;
#pragma unroll
        for (int ni = 0; ni < 8; ++ni) {
            float e = vm[ni] ? __expf(acc[ni][r] * SCL - mx) : 0.f;
            acc[ni][r] = e;
            s += e;
        }
        s += __shfl_xor(s, 1);
        s += __shfl_xor(s, 2);
        s += __shfl_xor(s, 4);
        s += __shfl_xor(s, 8);
        float inv = 1.0f / s;
#pragma unroll
        for (int ni = 0; ni < 8; ++ni) acc[ni][r] *= inv;
    }
#pragma unroll
    for (int ni = 0; ni < 8; ++ni)
#pragma unroll
        for (int r = 0; r < 4; ++r) {
            int row = w * 16 + g * 4 + r;
            int col = ni * 16 + li;
            *(short*)(Pb + row * 256 + (((col >> 3) ^ (row & 7)) << 4) + ((col & 7) << 1)) =
                (short)bf16_1(acc[ni][r]);
        }

    f32x4 acc2[16];
#pragma unroll
    for (int j = 0; j < 16; ++j) acc2[j] = zero;

#pragma unroll 1
    for (int ch = 0; ch < 4; ++ch) {
#pragma unroll
        for (int j = 0; j < 4; ++j) {
            int row = j * 64 + (t >> 2);
            int slot = t & 3;
            int ss = slot ^ (row & 3);
            gload16(gpb + (size_t)row * 128 + ch * 32 + ss * 8,
                    &Gs[(j * 256 + t) * 8]);
        }
        __syncthreads();

        int prow = w * 16 + li;
        bf16x8 a2 = *(const bf16x8*)(Pb + prow * 256 + (((ch * 4 + g) ^ (prow & 7)) << 4));
#pragma unroll
        for (int cf = 0; cf < 16; ++cf) {
            int crow = cf * 16 + li;
            bf16x8 bv = *(const bf16x8*)((const char*)Gs + crow * 64 + ((g ^ (crow & 3)) << 4));
            acc2[cf] = __builtin_amdgcn_mfma_f32_16x16x32_bf16(a2, bv, acc2[cf], 0, 0, 0);
        }
        __syncthreads();
    }

#pragma unroll
    for (int cf = 0; cf < 16; ++cf) {
        int c = cf * 16 + li;
        int cib = w * 16 + g * 4;
        int e0 = c * 64 + (cib ^ ((li & 7) << 3));
        unsigned d0 = bf16_pack(acc2[cf][0], acc2[cf][1]);
        unsigned d1 = bf16_pack(acc2[cf][2], acc2[cf][3]);
        *(unsigned*)(smem + (size_t)e0 * 2) = d0;
        *(unsigned*)(smem + (size_t)e0 * 2 + 4) = d1;
    }

    __syncthreads();

    {
        int c = t;
        u16* dst = y2T + ((size_t)b * HWN + rr * 256 + c) * 256 + ci0;
#pragma unroll
        for (int j = 0; j < 8; ++j) {
            uint4 v = *(const uint4*)(smem + c * 128 + ((j ^ (c & 7)) << 4));
            *(uint4*)(dst + j * 8) = v;
        }
    }
}

extern "C" void kernel_launch(void* const* d_in, const int* in_sizes, int n_in,
                              void* d_out, int out_size, void* d_ws, size_t ws_size,
                              hipStream_t stream)
{
    const float* x       = (const float*)d_in[0];
    const float* phi_w   = (const float*)d_in[1];
    const float* phi_b   = (const float*)d_in[2];
    const float* theta_w = (const float*)d_in[3];
    const float* theta_b = (const float*)d_in[4];
    const float* gamma_w = (const float*)d_in[5];
    const float* gamma_b = (const float*)d_in[6];
    const float* W_w     = (const float*)d_in[7];
    const float* W_b     = (const float*)d_in[8];
    float* out = (float*)d_out;

    char* p = (char*)d_ws;
    u16* xT     = (u16*)p;  p += (size_t)NB * HWN * CIN * 2;   // 75.5 MB
    u16* phi_bf = (u16*)p;  p += (size_t)NB * OIN * HWN * 2;   // 37.7 MB
    u16* th_y2  = (u16*)p;  p += (size_t)NB * OIN * HWN * 2;   // 37.7 MB (theta, then y2T)
    float* xp   = (float*)p; p += (size_t)NB * CIN * KP * 4;
    u16* tpT    = (u16*)p;  p += (size_t)NB * 128 * 256 * 2;
    u16* gp     = (u16*)p;  p += (size_t)NB * 256 * 128 * 2;
    u16* Wcat   = (u16*)p;  p += 512 * 512 * 2;
    u16* Wwb    = (u16*)p;  p += 512 * 256 * 2;
    float* bs   = (float*)p; p += (size_t)NB * CIN * 576 * 4;  // 9.4 MB

    castw_kernel<<<1536, 256, 0, stream>>>(phi_w, theta_w, W_w, Wcat, Wwb);
    castx_kernel<<<dim3(144, 8, NB), 256, 0, stream>>>(x, xT);
    // pool from xT (bf16, L3-hot): stage A block-sums (4608 blocks), stage B
    poolx_bs_kernel<<<dim3(576, NB), 256, 0, stream>>>(xT, bs);
    poolx_fin_kernel<<<dim3(16, NB), 256, 0, stream>>>(bs, xp);
    gemm_kernel<512, 0><<<dim3(72 * 4 * NB), 256, 0, stream>>>(
        xT, Wcat, phi_b, theta_b, nullptr, phi_bf, th_y2);
    pool_t_kernel<<<dim3(NB * OIN), 256, 0, stream>>>(th_y2, tpT);
    gammap_kernel<<<dim3(16, NB), 256, 0, stream>>>(xp, gamma_w, gamma_b, gp);
    attn_kernel<<<dim3(144, NB), 256, 0, stream>>>(phi_bf, tpT, gp, th_y2);
    gemm_kernel<256, 1><<<dim3(72 * 4 * NB), 256, 0, stream>>>(
        th_y2, Wwb, W_b, nullptr, x, out, nullptr);
}

// Round 17
// 306.363 us; speedup vs baseline: 1.0465x; 1.0309x over previous
//
#include <hip/hip_runtime.h>

#define NB 8
#define CIN 512
#define OIN 256
#define HWN 9216
#define KP 110
#define SCL 0.10206207261596577f  // 9216^(-0.25)

typedef __attribute__((ext_vector_type(8))) short bf16x8;
typedef __attribute__((ext_vector_type(4))) float f32x4;
typedef unsigned short u16;

__device__ inline unsigned bf16_1(float a) {
    unsigned u = __builtin_bit_cast(unsigned, a);
    return (u + 0x7fffu + ((u >> 16) & 1u)) >> 16;
}
__device__ inline unsigned bf16_pack(float a, float b) {
    return bf16_1(a) | (bf16_1(b) << 16);
}
__device__ inline float b2f(u16 u) {
    return __builtin_bit_cast(float, ((unsigned)u) << 16);
}

__device__ __forceinline__ void gload16(const u16* g, u16* l) {
    __builtin_amdgcn_global_load_lds(
        (const __attribute__((address_space(1))) unsigned int*)g,
        (__attribute__((address_space(3))) unsigned int*)l, 16, 0, 0);
}

// ---------------------------------------------------------------------------
// Weight cast: phi_w+theta_w -> Wcat bf16 [512][512]; W_w -> Wwb bf16 [512][256]
// ---------------------------------------------------------------------------
__global__ __launch_bounds__(256) void castw_kernel(
    const float* __restrict__ phi_w, const float* __restrict__ theta_w,
    const float* __restrict__ Ww,
    u16* __restrict__ Wcat, u16* __restrict__ Wwb)
{
    int i = blockIdx.x * 256 + threadIdx.x;
    if (i < 262144) {
        float v = (i < 131072) ? phi_w[i] : theta_w[i - 131072];
        Wcat[i] = (u16)bf16_1(v);
    } else {
        int j = i - 262144;
        Wwb[j] = (u16)bf16_1(Ww[j]);
    }
}

// ---------------------------------------------------------------------------
// castx: x fp32 [b][512 c][9216 hw] -> xT bf16 [b][9216 hw][512 c]
// ---------------------------------------------------------------------------
__global__ __launch_bounds__(256) void castx_kernel(
    const float* __restrict__ x, u16* __restrict__ xT)
{
    const int t = threadIdx.x;
    const int tx = t & 15, ty = t >> 4;
    const int b = blockIdx.z;
    const int c0 = blockIdx.y * 64;
    const int hw0 = blockIdx.x * 64;

    const float* xb = x + ((size_t)b * CIN + c0 + ty * 4) * HWN + hw0 + tx * 4;
    float4 v[4];
#pragma unroll
    for (int q = 0; q < 4; ++q)
        v[q] = *(const float4*)(xb + (size_t)q * HWN);

    u16* dst = xT + ((size_t)b * HWN + hw0 + tx * 4) * CIN + c0 + ty * 4;
    const float* f = (const float*)v;
#pragma unroll
    for (int p = 0; p < 4; ++p) {
        uint2 o = {bf16_pack(f[0 * 4 + p], f[1 * 4 + p]),
                   bf16_pack(f[2 * 4 + p], f[3 * 4 + p])};
        *(uint2*)(dst + (size_t)p * CIN) = o;
    }
}

// ---------------------------------------------------------------------------
// SPP pooling, fp32 input (x) -> xp [B][512][110] fp32 (proven R13 version)
// ---------------------------------------------------------------------------
__global__ __launch_bounds__(256) void pool_x_kernel(
    const float* __restrict__ in, float* __restrict__ out)
{
    __shared__ float ps[576];
    const int plane = blockIdx.x;
    const float* p = in + (size_t)plane * HWN;
    const int t = threadIdx.x;

    for (int i = t; i < 576; i += 256) {
        int bh = i / 24, bw = i % 24;
        float s = 0.f;
#pragma unroll
        for (int r = 0; r < 4; ++r) {
            float4 v = *(const float4*)&p[(bh * 4 + r) * 96 + bw * 4];
            s += v.x + v.y + v.z + v.w;
        }
        ps[i] = s;
    }
    __syncthreads();

    if (t < KP) {
        float s = 0.f;
        if (t == 0) {
            for (int i = 0; i < 576; ++i) s += ps[i];
            s *= (1.0f / 9216.0f);
        } else if (t < 10) {
            int idx = t - 1, bi = idx / 3, bj = idx % 3;
            for (int r = 0; r < 8; ++r)
                for (int c = 0; c < 8; ++c)
                    s += ps[(bi * 8 + r) * 24 + bj * 8 + c];
            s *= (1.0f / 1024.0f);
        } else if (t < 46) {
            int idx = t - 10, bi = idx / 6, bj = idx % 6;
            for (int r = 0; r < 4; ++r)
                for (int c = 0; c < 4; ++c)
                    s += ps[(bi * 4 + r) * 24 + bj * 4 + c];
            s *= (1.0f / 256.0f);
        } else {
            int idx = t - 46, bi = idx / 8, bj = idx % 8;
            for (int r = 0; r < 3; ++r)
                for (int c = 0; c < 3; ++c)
                    s += ps[(bi * 3 + r) * 24 + bj * 3 + c];
            s *= (1.0f / 144.0f);
        }
        out[(size_t)plane * KP + t] = s;
    }
}

// ---------------------------------------------------------------------------
// MFMA GEMM (proven R11 structure): BK=32, 3 buffers, counted vmcnt,
// 48 KB LDS, 3 blocks/CU. slot ^ ((row>>1)&3) swizzle -> <=2-way LDS aliasing.
// ---------------------------------------------------------------------------
template<int KDIM, int MODE>
__global__ __launch_bounds__(256, 3) void gemm_kernel(
    const u16* __restrict__ A,
    const u16* __restrict__ Bw,
    const float* __restrict__ b0, const float* __restrict__ b1,
    const float* __restrict__ resid,
    void* __restrict__ out0_, void* __restrict__ out1_)
{
    __shared__ u16 As[3][128 * 32];
    __shared__ u16 Bs[3][128 * 32];

    constexpr int NSTEP = KDIM / 32;
    constexpr int NWG = 72 * 4 * NB;

    const int id = blockIdx.x;
    const int swz = (id & 7) * (NWG / 8) + (id >> 3);
    const int u = swz % 288;
    const int bz = swz / 288;
    const int by = u & 3;
    const int bx = u >> 2;

    const int t = threadIdx.x;
    const int m0 = bx * 128;
    const int n0 = by * 128;
    const int w = t >> 6, l = t & 63;
    const int wr = w >> 1, wc = w & 1;
    const int g = l >> 4, li = l & 15;

    const u16* Ab = A + (size_t)bz * HWN * KDIM + (size_t)m0 * KDIM;
    const u16* Bb = Bw + (size_t)n0 * KDIM;

    f32x4 zero = {0.f, 0.f, 0.f, 0.f};
    f32x4 acc[4][4];
#pragma unroll
    for (int i = 0; i < 4; ++i)
#pragma unroll
        for (int j = 0; j < 4; ++j) acc[i][j] = zero;

    auto stage = [&](int step) {
        const int buf = step % 3;
#pragma unroll
        for (int j = 0; j < 2; ++j) {
            int c = j * 256 + t;
            int row = c >> 2, slot = c & 3;
            int ss = slot ^ ((row >> 1) & 3);
            gload16(Ab + (size_t)row * KDIM + step * 32 + ss * 8, &As[buf][c * 8]);
        }
#pragma unroll
        for (int j = 0; j < 2; ++j) {
            int c = j * 256 + t;
            int row = c >> 2, slot = c & 3;
            int ss = slot ^ ((row >> 1) & 3);
            gload16(Bb + (size_t)row * KDIM + step * 32 + ss * 8, &Bs[buf][c * 8]);
        }
    };

    stage(0);
    stage(1);

#pragma unroll 1
    for (int s = 0; s < NSTEP; ++s) {
        if (s + 2 < NSTEP) {
            stage(s + 2);
            asm volatile("s_waitcnt vmcnt(8)" ::: "memory");
        } else if (s + 1 < NSTEP) {
            asm volatile("s_waitcnt vmcnt(4)" ::: "memory");
        } else {
            asm volatile("s_waitcnt vmcnt(0)" ::: "memory");
        }
        __builtin_amdgcn_s_barrier();
        __builtin_amdgcn_sched_barrier(0);

        const int cb = s % 3;
        bf16x8 af[4], bv[4];
#pragma unroll
        for (int mi = 0; mi < 4; ++mi) {
            int r = wr * 64 + mi * 16 + li;
            int sl = g ^ ((r >> 1) & 3);
            af[mi] = *(const bf16x8*)&As[cb][r * 32 + sl * 8];
        }
#pragma unroll
        for (int ni = 0; ni < 4; ++ni) {
            int r = wc * 64 + ni * 16 + li;
            int sl = g ^ ((r >> 1) & 3);
            bv[ni] = *(const bf16x8*)&Bs[cb][r * 32 + sl * 8];
        }
#pragma unroll
        for (int mi = 0; mi < 4; ++mi)
#pragma unroll
            for (int ni = 0; ni < 4; ++ni)
                acc[mi][ni] = __builtin_amdgcn_mfma_f32_16x16x32_bf16(
                    af[mi], bv[ni], acc[mi][ni], 0, 0, 0);

        __builtin_amdgcn_s_barrier();
    }

#pragma unroll
    for (int ni = 0; ni < 4; ++ni) {
        int n = n0 + wc * 64 + ni * 16 + li;
        if constexpr (MODE == 0) {
            float bias = (n < 256) ? b0[n] : b1[n - 256];
            u16* dst = (u16*)((n < 256) ? out0_ : out1_) + ((size_t)bz * 256 + (n & 255)) * HWN;
#pragma unroll
            for (int mi = 0; mi < 4; ++mi) {
                int m = m0 + wr * 64 + mi * 16 + (g << 2);
                f32x4 v = acc[mi][ni];
                float e0 = fmaxf(v.x + bias, 0.f), e1 = fmaxf(v.y + bias, 0.f);
                float e2 = fmaxf(v.z + bias, 0.f), e3 = fmaxf(v.w + bias, 0.f);
                uint2 pk = {bf16_pack(e0, e1), bf16_pack(e2, e3)};
                *(uint2*)(dst + m) = pk;
            }
        } else {
            float bias = b0[n];
            float* dst = (float*)out0_ + ((size_t)bz * 512 + n) * HWN;
            const float* res = resid + ((size_t)bz * 512 + n) * HWN;
#pragma unroll
            for (int mi = 0; mi < 4; ++mi) {
                int m = m0 + wr * 64 + mi * 16 + (g << 2);
                f32x4 v = acc[mi][ni];
                float4 rx = *(const float4*)(res + m);
                float4 o = {v.x + bias + rx.x, v.y + bias + rx.y,
                            v.z + bias + rx.z, v.w + bias + rx.w};
                *(float4*)(dst + m) = o;
            }
        }
    }
}

// ---------------------------------------------------------------------------
// SPP pooling, bf16 input (theta) -> tpT [B][128][256] bf16 transposed, padded
// ---------------------------------------------------------------------------
__global__ __launch_bounds__(256) void pool_t_kernel(
    const u16* __restrict__ in, u16* __restrict__ outT)
{
    __shared__ float ps[576];
    const int plane = blockIdx.x;
    const int b = plane >> 8, c = plane & 255;
    const u16* p = in + (size_t)plane * HWN;
    const int t = threadIdx.x;

    for (int i = t; i < 576; i += 256) {
        int bh = i / 24, bw = i % 24;
        float s = 0.f;
#pragma unroll
        for (int r = 0; r < 4; ++r) {
            ushort4 v = *(const ushort4*)&p[(bh * 4 + r) * 96 + bw * 4];
            s += b2f(v.x) + b2f(v.y) + b2f(v.z) + b2f(v.w);
        }
        ps[i] = s;
    }
    __syncthreads();

    if (t < 128) {
        float s = 0.f;
        if (t == 0) {
            for (int i = 0; i < 576; ++i) s += ps[i];
            s *= (1.0f / 9216.0f);
        } else if (t < 10) {
            int idx = t - 1, bi = idx / 3, bj = idx % 3;
            for (int r = 0; r < 8; ++r)
                for (int cc = 0; cc < 8; ++cc)
                    s += ps[(bi * 8 + r) * 24 + bj * 8 + cc];
            s *= (1.0f / 1024.0f);
        } else if (t < 46) {
            int idx = t - 10, bi = idx / 6, bj = idx % 6;
            for (int r = 0; r < 4; ++r)
                for (int cc = 0; cc < 4; ++cc)
                    s += ps[(bi * 4 + r) * 24 + bj * 4 + cc];
            s *= (1.0f / 256.0f);
        } else if (t < KP) {
            int idx = t - 46, bi = idx / 8, bj = idx % 8;
            for (int r = 0; r < 3; ++r)
                for (int cc = 0; cc < 3; ++cc)
                    s += ps[(bi * 3 + r) * 24 + bj * 3 + cc];
            s *= (1.0f / 144.0f);
        } else {
            s = 0.f;
        }
        outT[((size_t)b * 128 + t) * 256 + c] = (u16)bf16_1(s);
    }
}

// ---------------------------------------------------------------------------
// gamma_p k-minor, L2-efficient: block = 8 k values x 256 o.
// ---------------------------------------------------------------------------
__global__ __launch_bounds__(256) void gammap_kernel(
    const float* __restrict__ xp,   // [B][512][110]
    const float* __restrict__ gw,   // [256][512]
    const float* __restrict__ gb,   // [256]
    u16* __restrict__ gp)           // [B][256][128]
{
    __shared__ float xc[8][512];
    const int kb = blockIdx.x * 8, b = blockIdx.y;
    const int t = threadIdx.x;

#pragma unroll
    for (int j = 0; j < 16; ++j) {
        int idx = j * 256 + t;
        int kk = idx >> 9, c = idx & 511;
        int k = kb + kk;
        xc[kk][c] = (k < KP) ? xp[((size_t)b * CIN + c) * KP + k] : 0.f;
    }
    __syncthreads();

    float bias = gb[t];
    float acc[8];
#pragma unroll
    for (int kk = 0; kk < 8; ++kk) acc[kk] = bias;

    const float* wrow = gw + (size_t)t * CIN;
#pragma unroll 2
    for (int c = 0; c < CIN; c += 4) {
        float4 wv = *(const float4*)&wrow[c];
#pragma unroll
        for (int kk = 0; kk < 8; ++kk) {
            acc[kk] = fmaf(wv.x, xc[kk][c], acc[kk]);
            acc[kk] = fmaf(wv.y, xc[kk][c + 1], acc[kk]);
            acc[kk] = fmaf(wv.z, xc[kk][c + 2], acc[kk]);
            acc[kk] = fmaf(wv.w, xc[kk][c + 3], acc[kk]);
        }
    }

    ushort4 o0, o1;
    o0.x = (u16)bf16_1(acc[0]); o0.y = (u16)bf16_1(acc[1]);
    o0.z = (u16)bf16_1(acc[2]); o0.w = (u16)bf16_1(acc[3]);
    o1.x = (u16)bf16_1(acc[4]); o1.y = (u16)bf16_1(acc[5]);
    o1.z = (u16)bf16_1(acc[6]); o1.w = (u16)bf16_1(acc[7]);
    u16* dst = gp + ((size_t)b * 256 + t) * 128 + kb;
    *(ushort4*)(dst) = o0;
    *(ushort4*)(dst + 4) = o1;
}

// ---------------------------------------------------------------------------
// MFMA attention, 64-ci blocks (R10 structure, setprio variant from R13).
// ---------------------------------------------------------------------------
__global__ __launch_bounds__(256, 4) void attn_kernel(
    const u16* __restrict__ phi,   // [B][256][9216] bf16
    const u16* __restrict__ tpT,   // [B][128][256] bf16
    const u16* __restrict__ gp,    // [B][256][128] bf16
    u16* __restrict__ y2T)         // [B][9216 hw'][256 ci] bf16
{
    __shared__ __align__(16) char smem[40960];
    u16* As = (u16*)smem;
    u16* Bs = (u16*)(smem + 8192);
    char* Pb = smem + 24576;
    u16* Gs = (u16*)smem;

    const int t = threadIdx.x;
    const int w = t >> 6, l = t & 63;
    const int g = l >> 4, li = l & 15;
    const int b = blockIdx.y;
    const int rr = blockIdx.x >> 2;
    const int ci0 = (blockIdx.x & 3) << 6;

    const u16* phib = phi + (size_t)b * (OIN * HWN);
    const u16* tpb  = tpT + (size_t)b * (128 * 256);
    const u16* gpb  = gp  + (size_t)b * (256 * 128);

    const int srow = t >> 3;
    const int su = t & 7;

    f32x4 zero = {0.f, 0.f, 0.f, 0.f};
    f32x4 acc[8];
#pragma unroll
    for (int j = 0; j < 8; ++j) acc[j] = zero;

    for (int kt = 0; kt < 256; kt += 64) {
#pragma unroll
        for (int cc = 0; cc < 2; ++cc) {
            int row = cc * 32 + srow;
            int ss = su ^ (row & 7);
            gload16(phib + (size_t)(ci0 + row) * HWN + rr * 256 + kt + ss * 8,
                    &As[(row * 8 + su) * 8]);
        }
#pragma unroll
        for (int cc = 0; cc < 4; ++cc) {
            int row = cc * 32 + srow;
            int ss = su ^ (row & 7);
            gload16(tpb + (size_t)row * 256 + kt + ss * 8,
                    &Bs[(row * 8 + su) * 8]);
        }
        __syncthreads();

#pragma unroll
        for (int h = 0; h < 2; ++h) {
            int r = w * 16 + li;
            bf16x8 af = *(const bf16x8*)&As[r * 64 + (((h * 4 + g) ^ (r & 7)) << 3)];
            bf16x8 bfr[8];
#pragma unroll
            for (int ni = 0; ni < 8; ++ni) {
                int rb = ni * 16 + li;
                bfr[ni] = *(const bf16x8*)&Bs[rb * 64 + (((h * 4 + g) ^ (rb & 7)) << 3)];
            }
            __builtin_amdgcn_s_setprio(1);
#pragma unroll
            for (int ni = 0; ni < 8; ++ni)
                acc[ni] = __builtin_amdgcn_mfma_f32_16x16x32_bf16(
                    af, bfr[ni], acc[ni], 0, 0, 0);
            __builtin_amdgcn_s_setprio(0);
        }
        __syncthreads();
    }

    bool vm[8];
#pragma unroll
    for (int ni = 0; ni < 8; ++ni) vm[ni] = (ni * 16 + li) < KP;

#pragma unroll
    for (int r = 0; r < 4; ++r) {
        float mx = -1e30f;
#pragma unroll
        for (int ni = 0; ni < 8; ++ni)
            if (vm[ni]) mx = fmaxf(mx, acc[ni][r] * SCL);
        mx = fmaxf(mx, __shfl_xor(mx, 1));
        mx = fmaxf(mx, __shfl_xor(mx, 2));
        mx = fmaxf(mx, __shfl_xor(mx, 4));
        mx = fmaxf(mx, __shfl_xor(mx, 8));
        float s = 0.f;
#pragma unroll
        for (int ni = 0; ni < 8; ++ni) {
            float e = vm[ni] ? __expf(acc[ni][r] * SCL - mx) : 0.f;
            acc[ni][r] = e;
            s += e;
        }
        s += __shfl_xor(s, 1);
        s += __shfl_xor(s, 2);
        s += __shfl_xor(s, 4);
        s += __shfl_xor(s, 8);
        float inv = 1.0f / s;
#pragma unroll
        for (int ni = 0; ni < 8; ++ni) acc[ni][r] *= inv;
    }
#pragma unroll
    for (int ni = 0; ni < 8; ++ni)
#pragma unroll
        for (int r = 0; r < 4; ++r) {
            int row = w * 16 + g * 4 + r;
            int col = ni * 16 + li;
            *(short*)(Pb + row * 256 + (((col >> 3) ^ (row & 7)) << 4) + ((col & 7) << 1)) =
                (short)bf16_1(acc[ni][r]);
        }

    f32x4 acc2[16];
#pragma unroll
    for (int j = 0; j < 16; ++j) acc2[j] = zero;

#pragma unroll 1
    for (int ch = 0; ch < 4; ++ch) {
#pragma unroll
        for (int j = 0; j < 4; ++j) {
            int row = j * 64 + (t >> 2);
            int slot = t & 3;
            int ss = slot ^ (row & 3);
            gload16(gpb + (size_t)row * 128 + ch * 32 + ss * 8,
                    &Gs[(j * 256 + t) * 8]);
        }
        __syncthreads();

        int prow = w * 16 + li;
        bf16x8 a2 = *(const bf16x8*)(Pb + prow * 256 + (((ch * 4 + g) ^ (prow & 7)) << 4));
        __builtin_amdgcn_s_setprio(1);
#pragma unroll
        for (int cf = 0; cf < 16; ++cf) {
            int crow = cf * 16 + li;
            bf16x8 bv = *(const bf16x8*)((const char*)Gs + crow * 64 + ((g ^ (crow & 3)) << 4));
            acc2[cf] = __builtin_amdgcn_mfma_f32_16x16x32_bf16(a2, bv, acc2[cf], 0, 0, 0);
        }
        __builtin_amdgcn_s_setprio(0);
        __syncthreads();
    }

#pragma unroll
    for (int cf = 0; cf < 16; ++cf) {
        int c = cf * 16 + li;
        int cib = w * 16 + g * 4;
        int e0 = c * 64 + (cib ^ ((li & 7) << 3));
        unsigned d0 = bf16_pack(acc2[cf][0], acc2[cf][1]);
        unsigned d1 = bf16_pack(acc2[cf][2], acc2[cf][3]);
        *(unsigned*)(smem + (size_t)e0 * 2) = d0;
        *(unsigned*)(smem + (size_t)e0 * 2 + 4) = d1;
    }

    __syncthreads();

    {
        int c = t;
        u16* dst = y2T + ((size_t)b * HWN + rr * 256 + c) * 256 + ci0;
#pragma unroll
        for (int j = 0; j < 8; ++j) {
            uint4 v = *(const uint4*)(smem + c * 128 + ((j ^ (c & 7)) << 4));
            *(uint4*)(dst + j * 8) = v;
        }
    }
}

extern "C" void kernel_launch(void* const* d_in, const int* in_sizes, int n_in,
                              void* d_out, int out_size, void* d_ws, size_t ws_size,
                              hipStream_t stream)
{
    const float* x       = (const float*)d_in[0];
    const float* phi_w   = (const float*)d_in[1];
    const float* phi_b   = (const float*)d_in[2];
    const float* theta_w = (const float*)d_in[3];
    const float* theta_b = (const float*)d_in[4];
    const float* gamma_w = (const float*)d_in[5];
    const float* gamma_b = (const float*)d_in[6];
    const float* W_w     = (const float*)d_in[7];
    const float* W_b     = (const float*)d_in[8];
    float* out = (float*)d_out;

    char* p = (char*)d_ws;
    u16* xT     = (u16*)p;  p += (size_t)NB * HWN * CIN * 2;   // 75.5 MB
    u16* phi_bf = (u16*)p;  p += (size_t)NB * OIN * HWN * 2;   // 37.7 MB
    u16* th_y2  = (u16*)p;  p += (size_t)NB * OIN * HWN * 2;   // 37.7 MB (theta, then y2T)
    float* xp   = (float*)p; p += (size_t)NB * CIN * KP * 4;
    u16* tpT    = (u16*)p;  p += (size_t)NB * 128 * 256 * 2;
    u16* gp     = (u16*)p;  p += (size_t)NB * 256 * 128 * 2;
    u16* Wcat   = (u16*)p;  p += 512 * 512 * 2;
    u16* Wwb    = (u16*)p;  p += 512 * 256 * 2;

    castw_kernel<<<1536, 256, 0, stream>>>(phi_w, theta_w, W_w, Wcat, Wwb);
    castx_kernel<<<dim3(144, 8, NB), 256, 0, stream>>>(x, xT);
    // pool_x right after castx: x still L3-resident from castx's read
    pool_x_kernel<<<dim3(NB * CIN), 256, 0, stream>>>(x, xp);
    gemm_kernel<512, 0><<<dim3(72 * 4 * NB), 256, 0, stream>>>(
        xT, Wcat, phi_b, theta_b, nullptr, phi_bf, th_y2);
    pool_t_kernel<<<dim3(NB * OIN), 256, 0, stream>>>(th_y2, tpT);
    gammap_kernel<<<dim3(16, NB), 256, 0, stream>>>(xp, gamma_w, gamma_b, gp);
    attn_kernel<<<dim3(144, NB), 256, 0, stream>>>(phi_bf, tpT, gp, th_y2);
    gemm_kernel<256, 1><<<dim3(72 * 4 * NB), 256, 0, stream>>>(
        th_y2, Wwb, W_b, nullptr, x, out, nullptr);
}

// Round 18
// 289.957 us; speedup vs baseline: 1.1058x; 1.0566x over previous
//
#include <hip/hip_runtime.h>

#define NB 8
#define CIN 512
#define OIN 256
#define HWN 9216
#define KP 110
#define SCL 0.10206207261596577f  // 9216^(-0.25)

typedef __attribute__((ext_vector_type(8))) short bf16x8;
typedef __attribute__((ext_vector_type(4))) float f32x4;
typedef unsigned short u16;

__device__ inline unsigned bf16_1(float a) {
    unsigned u = __builtin_bit_cast(unsigned, a);
    return (u + 0x7fffu + ((u >> 16) & 1u)) >> 16;
}
__device__ inline unsigned bf16_pack(float a, float b) {
    return bf16_1(a) | (bf16_1(b) << 16);
}
__device__ inline float b2f(u16 u) {
    return __builtin_bit_cast(float, ((unsigned)u) << 16);
}

__device__ __forceinline__ void gload16(const u16* g, u16* l) {
    __builtin_amdgcn_global_load_lds(
        (const __attribute__((address_space(1))) unsigned int*)g,
        (__attribute__((address_space(3))) unsigned int*)l, 16, 0, 0);
}

// ---------------------------------------------------------------------------
// prep: fused castw + castx + pool_x (mutually independent, inputs-only).
// grid = 9216 (castx) + 4096 (pool_x) + 1536 (castw) = 14848 blocks.
// Bodies verbatim from the verified standalone kernels; only index remap.
// ---------------------------------------------------------------------------
__global__ __launch_bounds__(256) void prep_kernel(
    const float* __restrict__ x, u16* __restrict__ xT, float* __restrict__ xp,
    const float* __restrict__ phi_w, const float* __restrict__ theta_w,
    const float* __restrict__ Ww,
    u16* __restrict__ Wcat, u16* __restrict__ Wwb)
{
    __shared__ float ps[576];
    const int bid = blockIdx.x;
    const int t = threadIdx.x;

    if (bid < 9216) {
        // ---- castx: x fp32 [b][512][9216] -> xT bf16 [b][9216][512] ----
        const int bx = bid % 144;
        const int cy = (bid / 144) & 7;
        const int b = bid / 1152;
        const int tx = t & 15, ty = t >> 4;
        const int c0 = cy * 64;
        const int hw0 = bx * 64;

        const float* xb = x + ((size_t)b * CIN + c0 + ty * 4) * HWN + hw0 + tx * 4;
        float4 v[4];
#pragma unroll
        for (int q = 0; q < 4; ++q)
            v[q] = *(const float4*)(xb + (size_t)q * HWN);

        u16* dst = xT + ((size_t)b * HWN + hw0 + tx * 4) * CIN + c0 + ty * 4;
        const float* f = (const float*)v;
#pragma unroll
        for (int p = 0; p < 4; ++p) {
            uint2 o = {bf16_pack(f[0 * 4 + p], f[1 * 4 + p]),
                       bf16_pack(f[2 * 4 + p], f[3 * 4 + p])};
            *(uint2*)(dst + (size_t)p * CIN) = o;
        }
    } else if (bid < 13312) {
        // ---- pool_x: x fp32 plane -> xp [plane][110] ----
        const int plane = bid - 9216;
        const float* p = x + (size_t)plane * HWN;

        for (int i = t; i < 576; i += 256) {
            int bh = i / 24, bw = i % 24;
            float s = 0.f;
#pragma unroll
            for (int r = 0; r < 4; ++r) {
                float4 v = *(const float4*)&p[(bh * 4 + r) * 96 + bw * 4];
                s += v.x + v.y + v.z + v.w;
            }
            ps[i] = s;
        }
        __syncthreads();

        if (t < KP) {
            float s = 0.f;
            if (t == 0) {
                for (int i = 0; i < 576; ++i) s += ps[i];
                s *= (1.0f / 9216.0f);
            } else if (t < 10) {
                int idx = t - 1, bi = idx / 3, bj = idx % 3;
                for (int r = 0; r < 8; ++r)
                    for (int c = 0; c < 8; ++c)
                        s += ps[(bi * 8 + r) * 24 + bj * 8 + c];
                s *= (1.0f / 1024.0f);
            } else if (t < 46) {
                int idx = t - 10, bi = idx / 6, bj = idx % 6;
                for (int r = 0; r < 4; ++r)
                    for (int c = 0; c < 4; ++c)
                        s += ps[(bi * 4 + r) * 24 + bj * 4 + c];
                s *= (1.0f / 256.0f);
            } else {
                int idx = t - 46, bi = idx / 8, bj = idx % 8;
                for (int r = 0; r < 3; ++r)
                    for (int c = 0; c < 3; ++c)
                        s += ps[(bi * 3 + r) * 24 + bj * 3 + c];
                s *= (1.0f / 144.0f);
            }
            xp[(size_t)plane * KP + t] = s;
        }
    } else {
        // ---- castw ----
        int i = (bid - 13312) * 256 + t;
        if (i < 262144) {
            float v = (i < 131072) ? phi_w[i] : theta_w[i - 131072];
            Wcat[i] = (u16)bf16_1(v);
        } else {
            int j = i - 262144;
            Wwb[j] = (u16)bf16_1(Ww[j]);
        }
    }
}

// ---------------------------------------------------------------------------
// MFMA GEMM (proven R11 structure): BK=32, 3 buffers, counted vmcnt,
// 48 KB LDS, 3 blocks/CU. slot ^ ((row>>1)&3) swizzle -> <=2-way LDS aliasing.
// ---------------------------------------------------------------------------
template<int KDIM, int MODE>
__global__ __launch_bounds__(256, 3) void gemm_kernel(
    const u16* __restrict__ A,
    const u16* __restrict__ Bw,
    const float* __restrict__ b0, const float* __restrict__ b1,
    const float* __restrict__ resid,
    void* __restrict__ out0_, void* __restrict__ out1_)
{
    __shared__ u16 As[3][128 * 32];
    __shared__ u16 Bs[3][128 * 32];

    constexpr int NSTEP = KDIM / 32;
    constexpr int NWG = 72 * 4 * NB;

    const int id = blockIdx.x;
    const int swz = (id & 7) * (NWG / 8) + (id >> 3);
    const int u = swz % 288;
    const int bz = swz / 288;
    const int by = u & 3;
    const int bx = u >> 2;

    const int t = threadIdx.x;
    const int m0 = bx * 128;
    const int n0 = by * 128;
    const int w = t >> 6, l = t & 63;
    const int wr = w >> 1, wc = w & 1;
    const int g = l >> 4, li = l & 15;

    const u16* Ab = A + (size_t)bz * HWN * KDIM + (size_t)m0 * KDIM;
    const u16* Bb = Bw + (size_t)n0 * KDIM;

    f32x4 zero = {0.f, 0.f, 0.f, 0.f};
    f32x4 acc[4][4];
#pragma unroll
    for (int i = 0; i < 4; ++i)
#pragma unroll
        for (int j = 0; j < 4; ++j) acc[i][j] = zero;

    auto stage = [&](int step) {
        const int buf = step % 3;
#pragma unroll
        for (int j = 0; j < 2; ++j) {
            int c = j * 256 + t;
            int row = c >> 2, slot = c & 3;
            int ss = slot ^ ((row >> 1) & 3);
            gload16(Ab + (size_t)row * KDIM + step * 32 + ss * 8, &As[buf][c * 8]);
        }
#pragma unroll
        for (int j = 0; j < 2; ++j) {
            int c = j * 256 + t;
            int row = c >> 2, slot = c & 3;
            int ss = slot ^ ((row >> 1) & 3);
            gload16(Bb + (size_t)row * KDIM + step * 32 + ss * 8, &Bs[buf][c * 8]);
        }
    };

    stage(0);
    stage(1);

#pragma unroll 1
    for (int s = 0; s < NSTEP; ++s) {
        if (s + 2 < NSTEP) {
            stage(s + 2);
            asm volatile("s_waitcnt vmcnt(8)" ::: "memory");
        } else if (s + 1 < NSTEP) {
            asm volatile("s_waitcnt vmcnt(4)" ::: "memory");
        } else {
            asm volatile("s_waitcnt vmcnt(0)" ::: "memory");
        }
        __builtin_amdgcn_s_barrier();
        __builtin_amdgcn_sched_barrier(0);

        const int cb = s % 3;
        bf16x8 af[4], bv[4];
#pragma unroll
        for (int mi = 0; mi < 4; ++mi) {
            int r = wr * 64 + mi * 16 + li;
            int sl = g ^ ((r >> 1) & 3);
            af[mi] = *(const bf16x8*)&As[cb][r * 32 + sl * 8];
        }
#pragma unroll
        for (int ni = 0; ni < 4; ++ni) {
            int r = wc * 64 + ni * 16 + li;
            int sl = g ^ ((r >> 1) & 3);
            bv[ni] = *(const bf16x8*)&Bs[cb][r * 32 + sl * 8];
        }
#pragma unroll
        for (int mi = 0; mi < 4; ++mi)
#pragma unroll
            for (int ni = 0; ni < 4; ++ni)
                acc[mi][ni] = __builtin_amdgcn_mfma_f32_16x16x32_bf16(
                    af[mi], bv[ni], acc[mi][ni], 0, 0, 0);

        __builtin_amdgcn_s_barrier();
    }

#pragma unroll
    for (int ni = 0; ni < 4; ++ni) {
        int n = n0 + wc * 64 + ni * 16 + li;
        if constexpr (MODE == 0) {
            float bias = (n < 256) ? b0[n] : b1[n - 256];
            u16* dst = (u16*)((n < 256) ? out0_ : out1_) + ((size_t)bz * 256 + (n & 255)) * HWN;
#pragma unroll
            for (int mi = 0; mi < 4; ++mi) {
                int m = m0 + wr * 64 + mi * 16 + (g << 2);
                f32x4 v = acc[mi][ni];
                float e0 = fmaxf(v.x + bias, 0.f), e1 = fmaxf(v.y + bias, 0.f);
                float e2 = fmaxf(v.z + bias, 0.f), e3 = fmaxf(v.w + bias, 0.f);
                uint2 pk = {bf16_pack(e0, e1), bf16_pack(e2, e3)};
                *(uint2*)(dst + m) = pk;
            }
        } else {
            float bias = b0[n];
            float* dst = (float*)out0_ + ((size_t)bz * 512 + n) * HWN;
            const float* res = resid + ((size_t)bz * 512 + n) * HWN;
#pragma unroll
            for (int mi = 0; mi < 4; ++mi) {
                int m = m0 + wr * 64 + mi * 16 + (g << 2);
                f32x4 v = acc[mi][ni];
                float4 rx = *(const float4*)(res + m);
                float4 o = {v.x + bias + rx.x, v.y + bias + rx.y,
                            v.z + bias + rx.z, v.w + bias + rx.w};
                *(float4*)(dst + m) = o;
            }
        }
    }
}

// ---------------------------------------------------------------------------
// mid: fused pool_t + gammap (both independent; inputs ready after gemm0).
// grid = 2048 (pool_t) + 128 (gammap) = 2176 blocks. LDS unioned (16 KB).
// ---------------------------------------------------------------------------
__global__ __launch_bounds__(256) void mid_kernel(
    const u16* __restrict__ theta_bf, u16* __restrict__ tpT,
    const float* __restrict__ xp, const float* __restrict__ gw,
    const float* __restrict__ gb, u16* __restrict__ gp)
{
    __shared__ __align__(16) char sh[16384];
    const int bid = blockIdx.x;
    const int t = threadIdx.x;

    if (bid < 2048) {
        // ---- pool_t: theta bf16 plane -> tpT [b][128][256] transposed ----
        float* ps = (float*)sh;
        const int b = bid >> 8, c = bid & 255;
        const u16* p = theta_bf + (size_t)bid * HWN;

        for (int i = t; i < 576; i += 256) {
            int bh = i / 24, bw = i % 24;
            float s = 0.f;
#pragma unroll
            for (int r = 0; r < 4; ++r) {
                ushort4 v = *(const ushort4*)&p[(bh * 4 + r) * 96 + bw * 4];
                s += b2f(v.x) + b2f(v.y) + b2f(v.z) + b2f(v.w);
            }
            ps[i] = s;
        }
        __syncthreads();

        if (t < 128) {
            float s = 0.f;
            if (t == 0) {
                for (int i = 0; i < 576; ++i) s += ps[i];
                s *= (1.0f / 9216.0f);
            } else if (t < 10) {
                int idx = t - 1, bi = idx / 3, bj = idx % 3;
                for (int r = 0; r < 8; ++r)
                    for (int cc = 0; cc < 8; ++cc)
                        s += ps[(bi * 8 + r) * 24 + bj * 8 + cc];
                s *= (1.0f / 1024.0f);
            } else if (t < 46) {
                int idx = t - 10, bi = idx / 6, bj = idx % 6;
                for (int r = 0; r < 4; ++r)
                    for (int cc = 0; cc < 4; ++cc)
                        s += ps[(bi * 4 + r) * 24 + bj * 4 + cc];
                s *= (1.0f / 256.0f);
            } else if (t < KP) {
                int idx = t - 46, bi = idx / 8, bj = idx % 8;
                for (int r = 0; r < 3; ++r)
                    for (int cc = 0; cc < 3; ++cc)
                        s += ps[(bi * 3 + r) * 24 + bj * 3 + cc];
                s *= (1.0f / 144.0f);
            } else {
                s = 0.f;
            }
            tpT[((size_t)b * 128 + t) * 256 + c] = (u16)bf16_1(s);
        }
    } else {
        // ---- gammap: gp[b][c][k] bf16, k padded to 128 ----
        float (*xc)[512] = (float (*)[512])sh;
        const int gidx = bid - 2048;
        const int kb = (gidx & 15) * 8, b = gidx >> 4;

#pragma unroll
        for (int j = 0; j < 16; ++j) {
            int idx = j * 256 + t;
            int kk = idx >> 9, c = idx & 511;
            int k = kb + kk;
            xc[kk][c] = (k < KP) ? xp[((size_t)b * CIN + c) * KP + k] : 0.f;
        }
        __syncthreads();

        float bias = gb[t];
        float acc[8];
#pragma unroll
        for (int kk = 0; kk < 8; ++kk) acc[kk] = bias;

        const float* wrow = gw + (size_t)t * CIN;
#pragma unroll 2
        for (int c = 0; c < CIN; c += 4) {
            float4 wv = *(const float4*)&wrow[c];
#pragma unroll
            for (int kk = 0; kk < 8; ++kk) {
                acc[kk] = fmaf(wv.x, xc[kk][c], acc[kk]);
                acc[kk] = fmaf(wv.y, xc[kk][c + 1], acc[kk]);
                acc[kk] = fmaf(wv.z, xc[kk][c + 2], acc[kk]);
                acc[kk] = fmaf(wv.w, xc[kk][c + 3], acc[kk]);
            }
        }

        ushort4 o0, o1;
        o0.x = (u16)bf16_1(acc[0]); o0.y = (u16)bf16_1(acc[1]);
        o0.z = (u16)bf16_1(acc[2]); o0.w = (u16)bf16_1(acc[3]);
        o1.x = (u16)bf16_1(acc[4]); o1.y = (u16)bf16_1(acc[5]);
        o1.z = (u16)bf16_1(acc[6]); o1.w = (u16)bf16_1(acc[7]);
        u16* dst = gp + ((size_t)b * 256 + t) * 128 + kb;
        *(ushort4*)(dst) = o0;
        *(ushort4*)(dst + 4) = o1;
    }
}

// ---------------------------------------------------------------------------
// MFMA attention, 64-ci blocks (R10 structure, setprio variant).
// ---------------------------------------------------------------------------
__global__ __launch_bounds__(256, 4) void attn_kernel(
    const u16* __restrict__ phi,   // [B][256][9216] bf16
    const u16* __restrict__ tpT,   // [B][128][256] bf16
    const u16* __restrict__ gp,    // [B][256][128] bf16
    u16* __restrict__ y2T)         // [B][9216 hw'][256 ci] bf16
{
    __shared__ __align__(16) char smem[40960];
    u16* As = (u16*)smem;
    u16* Bs = (u16*)(smem + 8192);
    char* Pb = smem + 24576;
    u16* Gs = (u16*)smem;

    const int t = threadIdx.x;
    const int w = t >> 6, l = t & 63;
    const int g = l >> 4, li = l & 15;
    const int b = blockIdx.y;
    const int rr = blockIdx.x >> 2;
    const int ci0 = (blockIdx.x & 3) << 6;

    const u16* phib = phi + (size_t)b * (OIN * HWN);
    const u16* tpb  = tpT + (size_t)b * (128 * 256);
    const u16* gpb  = gp  + (size_t)b * (256 * 128);

    const int srow = t >> 3;
    const int su = t & 7;

    f32x4 zero = {0.f, 0.f, 0.f, 0.f};
    f32x4 acc[8];
#pragma unroll
    for (int j = 0; j < 8; ++j) acc[j] = zero;

    for (int kt = 0; kt < 256; kt += 64) {
#pragma unroll
        for (int cc = 0; cc < 2; ++cc) {
            int row = cc * 32 + srow;
            int ss = su ^ (row & 7);
            gload16(phib + (size_t)(ci0 + row) * HWN + rr * 256 + kt + ss * 8,
                    &As[(row * 8 + su) * 8]);
        }
#pragma unroll
        for (int cc = 0; cc < 4; ++cc) {
            int row = cc * 32 + srow;
            int ss = su ^ (row & 7);
            gload16(tpb + (size_t)row * 256 + kt + ss * 8,
                    &Bs[(row * 8 + su) * 8]);
        }
        __syncthreads();

#pragma unroll
        for (int h = 0; h < 2; ++h) {
            int r = w * 16 + li;
            bf16x8 af = *(const bf16x8*)&As[r * 64 + (((h * 4 + g) ^ (r & 7)) << 3)];
            bf16x8 bfr[8];
#pragma unroll
            for (int ni = 0; ni < 8; ++ni) {
                int rb = ni * 16 + li;
                bfr[ni] = *(const bf16x8*)&Bs[rb * 64 + (((h * 4 + g) ^ (rb & 7)) << 3)];
            }
            __builtin_amdgcn_s_setprio(1);
#pragma unroll
            for (int ni = 0; ni < 8; ++ni)
                acc[ni] = __builtin_amdgcn_mfma_f32_16x16x32_bf16(
                    af, bfr[ni], acc[ni], 0, 0, 0);
            __builtin_amdgcn_s_setprio(0);
        }
        __syncthreads();
    }

    bool vm[8];
#pragma unroll
    for (int ni = 0; ni < 8; ++ni) vm[ni] = (ni * 16 + li) < KP;

#pragma unroll
    for (int r = 0; r < 4; ++r) {
        float mx = -1e30f;
#pragma unroll
        for (int ni = 0; ni < 8; ++ni)
            if (vm[ni]) mx = fmaxf(mx, acc[ni][r] * SCL);
        mx = fmaxf(mx, __shfl_xor(mx, 1));
        mx = fmaxf(mx, __shfl_xor(mx, 2));
        mx = fmaxf(mx, __shfl_xor(mx, 4));
        mx = fmaxf(mx, __shfl_xor(mx, 8));
        float s = 0.f;
#pragma unroll
        for (int ni = 0; ni < 8; ++ni) {
            float e = vm[ni] ? __expf(acc[ni][r] * SCL - mx) : 0.f;
            acc[ni][r] = e;
            s += e;
        }
        s += __shfl_xor(s, 1);
        s += __shfl_xor(s, 2);
        s += __shfl_xor(s, 4);
        s += __shfl_xor(s, 8);
        float inv = 1.0f / s;
#pragma unroll
        for (int ni = 0; ni < 8; ++ni) acc[ni][r] *= inv;
    }
#pragma unroll
    for (int ni = 0; ni < 8; ++ni)
#pragma unroll
        for (int r = 0; r < 4; ++r) {
            int row = w * 16 + g * 4 + r;
            int col = ni * 16 + li;
            *(short*)(Pb + row * 256 + (((col >> 3) ^ (row & 7)) << 4) + ((col & 7) << 1)) =
                (short)bf16_1(acc[ni][r]);
        }

    f32x4 acc2[16];
#pragma unroll
    for (int j = 0; j < 16; ++j) acc2[j] = zero;

#pragma unroll 1
    for (int ch = 0; ch < 4; ++ch) {
#pragma unroll
        for (int j = 0; j < 4; ++j) {
            int row = j * 64 + (t >> 2);
            int slot = t & 3;
            int ss = slot ^ (row & 3);
            gload16(gpb + (size_t)row * 128 + ch * 32 + ss * 8,
                    &Gs[(j * 256 + t) * 8]);
        }
        __syncthreads();

        int prow = w * 16 + li;
        bf16x8 a2 = *(const bf16x8*)(Pb + prow * 256 + (((ch * 4 + g) ^ (prow & 7)) << 4));
        __builtin_amdgcn_s_setprio(1);
#pragma unroll
        for (int cf = 0; cf < 16; ++cf) {
            int crow = cf * 16 + li;
            bf16x8 bv = *(const bf16x8*)((const char*)Gs + crow * 64 + ((g ^ (crow & 3)) << 4));
            acc2[cf] = __builtin_amdgcn_mfma_f32_16x16x32_bf16(a2, bv, acc2[cf], 0, 0, 0);
        }
        __builtin_amdgcn_s_setprio(0);
        __syncthreads();
    }

#pragma unroll
    for (int cf = 0; cf < 16; ++cf) {
        int c = cf * 16 + li;
        int cib = w * 16 + g * 4;
        int e0 = c * 64 + (cib ^ ((li & 7) << 3));
        unsigned d0 = bf16_pack(acc2[cf][0], acc2[cf][1]);
        unsigned d1 = bf16_pack(acc2[cf][2], acc2[cf][3]);
        *(unsigned*)(smem + (size_t)e0 * 2) = d0;
        *(unsigned*)(smem + (size_t)e0 * 2 + 4) = d1;
    }

    __syncthreads();

    {
        int c = t;
        u16* dst = y2T + ((size_t)b * HWN + rr * 256 + c) * 256 + ci0;
#pragma unroll
        for (int j = 0; j < 8; ++j) {
            uint4 v = *(const uint4*)(smem + c * 128 + ((j ^ (c & 7)) << 4));
            *(uint4*)(dst + j * 8) = v;
        }
    }
}

extern "C" void kernel_launch(void* const* d_in, const int* in_sizes, int n_in,
                              void* d_out, int out_size, void* d_ws, size_t ws_size,
                              hipStream_t stream)
{
    const float* x       = (const float*)d_in[0];
    const float* phi_w   = (const float*)d_in[1];
    const float* phi_b   = (const float*)d_in[2];
    const float* theta_w = (const float*)d_in[3];
    const float* theta_b = (const float*)d_in[4];
    const float* gamma_w = (const float*)d_in[5];
    const float* gamma_b = (const float*)d_in[6];
    const float* W_w     = (const float*)d_in[7];
    const float* W_b     = (const float*)d_in[8];
    float* out = (float*)d_out;

    char* p = (char*)d_ws;
    u16* xT     = (u16*)p;  p += (size_t)NB * HWN * CIN * 2;   // 75.5 MB
    u16* phi_bf = (u16*)p;  p += (size_t)NB * OIN * HWN * 2;   // 37.7 MB
    u16* th_y2  = (u16*)p;  p += (size_t)NB * OIN * HWN * 2;   // 37.7 MB (theta, then y2T)
    float* xp   = (float*)p; p += (size_t)NB * CIN * KP * 4;
    u16* tpT    = (u16*)p;  p += (size_t)NB * 128 * 256 * 2;
    u16* gp     = (u16*)p;  p += (size_t)NB * 256 * 128 * 2;
    u16* Wcat   = (u16*)p;  p += 512 * 512 * 2;
    u16* Wwb    = (u16*)p;  p += 512 * 256 * 2;

    prep_kernel<<<dim3(14848), 256, 0, stream>>>(
        x, xT, xp, phi_w, theta_w, W_w, Wcat, Wwb);
    gemm_kernel<512, 0><<<dim3(72 * 4 * NB), 256, 0, stream>>>(
        xT, Wcat, phi_b, theta_b, nullptr, phi_bf, th_y2);
    mid_kernel<<<dim3(2176), 256, 0, stream>>>(
        th_y2, tpT, xp, gamma_w, gamma_b, gp);
    attn_kernel<<<dim3(144, NB), 256, 0, stream>>>(phi_bf, tpT, gp, th_y2);
    gemm_kernel<256, 1><<<dim3(72 * 4 * NB), 256, 0, stream>>>(
        th_y2, Wwb, W_b, nullptr, x, out, nullptr);
}

// Round 19
// 285.646 us; speedup vs baseline: 1.1224x; 1.0151x over previous
//
#include <hip/hip_runtime.h>

#define NB 8
#define CIN 512
#define OIN 256
#define HWN 9216
#define KP 110
#define SCL 0.10206207261596577f  // 9216^(-0.25)

typedef __attribute__((ext_vector_type(8))) short bf16x8;
typedef __attribute__((ext_vector_type(4))) float f32x4;
typedef unsigned short u16;

__device__ inline unsigned bf16_1(float a) {
    unsigned u = __builtin_bit_cast(unsigned, a);
    return (u + 0x7fffu + ((u >> 16) & 1u)) >> 16;
}
__device__ inline unsigned bf16_pack(float a, float b) {
    return bf16_1(a) | (bf16_1(b) << 16);
}
__device__ inline float b2f(u16 u) {
    return __builtin_bit_cast(float, ((unsigned)u) << 16);
}

__device__ __forceinline__ void gload16(const u16* g, u16* l) {
    __builtin_amdgcn_global_load_lds(
        (const __attribute__((address_space(1))) unsigned int*)g,
        (__attribute__((address_space(3))) unsigned int*)l, 16, 0, 0);
}

// ---------------------------------------------------------------------------
// prep: fused castw + castx + pool_x (mutually independent, inputs-only).
// grid = 9216 (castx) + 4096 (pool_x) + 1536 (castw) = 14848 blocks.
// castx now LDS-bounced: coalesced 128B-per-8-lane uint4 global writes
// (was 8B/lane scattered at 4KB stride -> partial-line HBM writes).
// ---------------------------------------------------------------------------
__global__ __launch_bounds__(256) void prep_kernel(
    const float* __restrict__ x, u16* __restrict__ xT, float* __restrict__ xp,
    const float* __restrict__ phi_w, const float* __restrict__ theta_w,
    const float* __restrict__ Ww,
    u16* __restrict__ Wcat, u16* __restrict__ Wwb)
{
    __shared__ __align__(16) char sh[8192];
    const int bid = blockIdx.x;
    const int t = threadIdx.x;

    if (bid < 9216) {
        // ---- castx: x fp32 [b][512][9216] -> xT bf16 [b][9216][512] ----
        const int bx = bid % 144;
        const int cy = (bid / 144) & 7;
        const int b = bid / 1152;
        const int tx = t & 15, ty = t >> 4;
        const int c0 = cy * 64;
        const int hw0 = bx * 64;

        const float* xb = x + ((size_t)b * CIN + c0 + ty * 4) * HWN + hw0 + tx * 4;
        float4 v[4];
#pragma unroll
        for (int q = 0; q < 4; ++q)
            v[q] = *(const float4*)(xb + (size_t)q * HWN);

        // phase 1: transpose into LDS [64 hw][16 slots x 8B], XOR swizzle
        u16* ld = (u16*)sh;
        const float* f = (const float*)v;
        const int sb = (tx & 7) * 2;
#pragma unroll
        for (int i = 0; i < 4; ++i) {
            int row = tx * 4 + i;
            int sl = ty ^ sb;
            uint2 o = {bf16_pack(f[0 * 4 + i], f[1 * 4 + i]),
                       bf16_pack(f[2 * 4 + i], f[3 * 4 + i])};
            *(uint2*)((char*)ld + row * 128 + sl * 8) = o;
        }
        __syncthreads();

        // phase 2: coalesced stores, 8 lanes x uint4 = 128B per row segment
        const int row0 = t >> 3, p = t & 7;
#pragma unroll
        for (int jj = 0; jj < 2; ++jj) {
            int row = row0 + jj * 32;
            uint4 w = *(const uint4*)((char*)ld + row * 128 + 16 * (p ^ ((row >> 2) & 7)));
            *(uint4*)(xT + ((size_t)b * HWN + hw0 + row) * CIN + c0 + p * 8) = w;
        }
    } else if (bid < 13312) {
        // ---- pool_x: x fp32 plane -> xp [plane][110] ----
        float* ps = (float*)sh;
        const int plane = bid - 9216;
        const float* p = x + (size_t)plane * HWN;

        for (int i = t; i < 576; i += 256) {
            int bh = i / 24, bw = i % 24;
            float s = 0.f;
#pragma unroll
            for (int r = 0; r < 4; ++r) {
                float4 v = *(const float4*)&p[(bh * 4 + r) * 96 + bw * 4];
                s += v.x + v.y + v.z + v.w;
            }
            ps[i] = s;
        }
        __syncthreads();

        if (t < KP) {
            float s = 0.f;
            if (t == 0) {
                for (int i = 0; i < 576; ++i) s += ps[i];
                s *= (1.0f / 9216.0f);
            } else if (t < 10) {
                int idx = t - 1, bi = idx / 3, bj = idx % 3;
                for (int r = 0; r < 8; ++r)
                    for (int c = 0; c < 8; ++c)
                        s += ps[(bi * 8 + r) * 24 + bj * 8 + c];
                s *= (1.0f / 1024.0f);
            } else if (t < 46) {
                int idx = t - 10, bi = idx / 6, bj = idx % 6;
                for (int r = 0; r < 4; ++r)
                    for (int c = 0; c < 4; ++c)
                        s += ps[(bi * 4 + r) * 24 + bj * 4 + c];
                s *= (1.0f / 256.0f);
            } else {
                int idx = t - 46, bi = idx / 8, bj = idx % 8;
                for (int r = 0; r < 3; ++r)
                    for (int c = 0; c < 3; ++c)
                        s += ps[(bi * 3 + r) * 24 + bj * 3 + c];
                s *= (1.0f / 144.0f);
            }
            xp[(size_t)plane * KP + t] = s;
        }
    } else {
        // ---- castw ----
        int i = (bid - 13312) * 256 + t;
        if (i < 262144) {
            float v = (i < 131072) ? phi_w[i] : theta_w[i - 131072];
            Wcat[i] = (u16)bf16_1(v);
        } else {
            int j = i - 262144;
            Wwb[j] = (u16)bf16_1(Ww[j]);
        }
    }
}

// ---------------------------------------------------------------------------
// MFMA GEMM (proven R11 structure): BK=32, 3 buffers, counted vmcnt,
// 48 KB LDS, 3 blocks/CU. slot ^ ((row>>1)&3) swizzle -> <=2-way LDS aliasing.
// ---------------------------------------------------------------------------
template<int KDIM, int MODE>
__global__ __launch_bounds__(256, 3) void gemm_kernel(
    const u16* __restrict__ A,
    const u16* __restrict__ Bw,
    const float* __restrict__ b0, const float* __restrict__ b1,
    const float* __restrict__ resid,
    void* __restrict__ out0_, void* __restrict__ out1_)
{
    __shared__ u16 As[3][128 * 32];
    __shared__ u16 Bs[3][128 * 32];

    constexpr int NSTEP = KDIM / 32;
    constexpr int NWG = 72 * 4 * NB;

    const int id = blockIdx.x;
    const int swz = (id & 7) * (NWG / 8) + (id >> 3);
    const int u = swz % 288;
    const int bz = swz / 288;
    const int by = u & 3;
    const int bx = u >> 2;

    const int t = threadIdx.x;
    const int m0 = bx * 128;
    const int n0 = by * 128;
    const int w = t >> 6, l = t & 63;
    const int wr = w >> 1, wc = w & 1;
    const int g = l >> 4, li = l & 15;

    const u16* Ab = A + (size_t)bz * HWN * KDIM + (size_t)m0 * KDIM;
    const u16* Bb = Bw + (size_t)n0 * KDIM;

    f32x4 zero = {0.f, 0.f, 0.f, 0.f};
    f32x4 acc[4][4];
#pragma unroll
    for (int i = 0; i < 4; ++i)
#pragma unroll
        for (int j = 0; j < 4; ++j) acc[i][j] = zero;

    auto stage = [&](int step) {
        const int buf = step % 3;
#pragma unroll
        for (int j = 0; j < 2; ++j) {
            int c = j * 256 + t;
            int row = c >> 2, slot = c & 3;
            int ss = slot ^ ((row >> 1) & 3);
            gload16(Ab + (size_t)row * KDIM + step * 32 + ss * 8, &As[buf][c * 8]);
        }
#pragma unroll
        for (int j = 0; j < 2; ++j) {
            int c = j * 256 + t;
            int row = c >> 2, slot = c & 3;
            int ss = slot ^ ((row >> 1) & 3);
            gload16(Bb + (size_t)row * KDIM + step * 32 + ss * 8, &Bs[buf][c * 8]);
        }
    };

    stage(0);
    stage(1);

#pragma unroll 1
    for (int s = 0; s < NSTEP; ++s) {
        if (s + 2 < NSTEP) {
            stage(s + 2);
            asm volatile("s_waitcnt vmcnt(8)" ::: "memory");
        } else if (s + 1 < NSTEP) {
            asm volatile("s_waitcnt vmcnt(4)" ::: "memory");
        } else {
            asm volatile("s_waitcnt vmcnt(0)" ::: "memory");
        }
        __builtin_amdgcn_s_barrier();
        __builtin_amdgcn_sched_barrier(0);

        const int cb = s % 3;
        bf16x8 af[4], bv[4];
#pragma unroll
        for (int mi = 0; mi < 4; ++mi) {
            int r = wr * 64 + mi * 16 + li;
            int sl = g ^ ((r >> 1) & 3);
            af[mi] = *(const bf16x8*)&As[cb][r * 32 + sl * 8];
        }
#pragma unroll
        for (int ni = 0; ni < 4; ++ni) {
            int r = wc * 64 + ni * 16 + li;
            int sl = g ^ ((r >> 1) & 3);
            bv[ni] = *(const bf16x8*)&Bs[cb][r * 32 + sl * 8];
        }
#pragma unroll
        for (int mi = 0; mi < 4; ++mi)
#pragma unroll
            for (int ni = 0; ni < 4; ++ni)
                acc[mi][ni] = __builtin_amdgcn_mfma_f32_16x16x32_bf16(
                    af[mi], bv[ni], acc[mi][ni], 0, 0, 0);

        __builtin_amdgcn_s_barrier();
    }

#pragma unroll
    for (int ni = 0; ni < 4; ++ni) {
        int n = n0 + wc * 64 + ni * 16 + li;
        if constexpr (MODE == 0) {
            float bias = (n < 256) ? b0[n] : b1[n - 256];
            u16* dst = (u16*)((n < 256) ? out0_ : out1_) + ((size_t)bz * 256 + (n & 255)) * HWN;
#pragma unroll
            for (int mi = 0; mi < 4; ++mi) {
                int m = m0 + wr * 64 + mi * 16 + (g << 2);
                f32x4 v = acc[mi][ni];
                float e0 = fmaxf(v.x + bias, 0.f), e1 = fmaxf(v.y + bias, 0.f);
                float e2 = fmaxf(v.z + bias, 0.f), e3 = fmaxf(v.w + bias, 0.f);
                uint2 pk = {bf16_pack(e0, e1), bf16_pack(e2, e3)};
                *(uint2*)(dst + m) = pk;
            }
        } else {
            float bias = b0[n];
            float* dst = (float*)out0_ + ((size_t)bz * 512 + n) * HWN;
            const float* res = resid + ((size_t)bz * 512 + n) * HWN;
#pragma unroll
            for (int mi = 0; mi < 4; ++mi) {
                int m = m0 + wr * 64 + mi * 16 + (g << 2);
                f32x4 v = acc[mi][ni];
                float4 rx = *(const float4*)(res + m);
                float4 o = {v.x + bias + rx.x, v.y + bias + rx.y,
                            v.z + bias + rx.z, v.w + bias + rx.w};
                *(float4*)(dst + m) = o;
            }
        }
    }
}

// ---------------------------------------------------------------------------
// mid: fused pool_t + gammap (both independent; inputs ready after gemm0).
// ---------------------------------------------------------------------------
__global__ __launch_bounds__(256) void mid_kernel(
    const u16* __restrict__ theta_bf, u16* __restrict__ tpT,
    const float* __restrict__ xp, const float* __restrict__ gw,
    const float* __restrict__ gb, u16* __restrict__ gp)
{
    __shared__ __align__(16) char sh[16384];
    const int bid = blockIdx.x;
    const int t = threadIdx.x;

    if (bid < 2048) {
        float* ps = (float*)sh;
        const int b = bid >> 8, c = bid & 255;
        const u16* p = theta_bf + (size_t)bid * HWN;

        for (int i = t; i < 576; i += 256) {
            int bh = i / 24, bw = i % 24;
            float s = 0.f;
#pragma unroll
            for (int r = 0; r < 4; ++r) {
                ushort4 v = *(const ushort4*)&p[(bh * 4 + r) * 96 + bw * 4];
                s += b2f(v.x) + b2f(v.y) + b2f(v.z) + b2f(v.w);
            }
            ps[i] = s;
        }
        __syncthreads();

        if (t < 128) {
            float s = 0.f;
            if (t == 0) {
                for (int i = 0; i < 576; ++i) s += ps[i];
                s *= (1.0f / 9216.0f);
            } else if (t < 10) {
                int idx = t - 1, bi = idx / 3, bj = idx % 3;
                for (int r = 0; r < 8; ++r)
                    for (int cc = 0; cc < 8; ++cc)
                        s += ps[(bi * 8 + r) * 24 + bj * 8 + cc];
                s *= (1.0f / 1024.0f);
            } else if (t < 46) {
                int idx = t - 10, bi = idx / 6, bj = idx % 6;
                for (int r = 0; r < 4; ++r)
                    for (int cc = 0; cc < 4; ++cc)
                        s += ps[(bi * 4 + r) * 24 + bj * 4 + cc];
                s *= (1.0f / 256.0f);
            } else if (t < KP) {
                int idx = t - 46, bi = idx / 8, bj = idx % 8;
                for (int r = 0; r < 3; ++r)
                    for (int cc = 0; cc < 3; ++cc)
                        s += ps[(bi * 3 + r) * 24 + bj * 3 + cc];
                s *= (1.0f / 144.0f);
            } else {
                s = 0.f;
            }
            tpT[((size_t)b * 128 + t) * 256 + c] = (u16)bf16_1(s);
        }
    } else {
        float (*xc)[512] = (float (*)[512])sh;
        const int gidx = bid - 2048;
        const int kb = (gidx & 15) * 8, b = gidx >> 4;

#pragma unroll
        for (int j = 0; j < 16; ++j) {
            int idx = j * 256 + t;
            int kk = idx >> 9, c = idx & 511;
            int k = kb + kk;
            xc[kk][c] = (k < KP) ? xp[((size_t)b * CIN + c) * KP + k] : 0.f;
        }
        __syncthreads();

        float bias = gb[t];
        float acc[8];
#pragma unroll
        for (int kk = 0; kk < 8; ++kk) acc[kk] = bias;

        const float* wrow = gw + (size_t)t * CIN;
#pragma unroll 2
        for (int c = 0; c < CIN; c += 4) {
            float4 wv = *(const float4*)&wrow[c];
#pragma unroll
            for (int kk = 0; kk < 8; ++kk) {
                acc[kk] = fmaf(wv.x, xc[kk][c], acc[kk]);
                acc[kk] = fmaf(wv.y, xc[kk][c + 1], acc[kk]);
                acc[kk] = fmaf(wv.z, xc[kk][c + 2], acc[kk]);
                acc[kk] = fmaf(wv.w, xc[kk][c + 3], acc[kk]);
            }
        }

        ushort4 o0, o1;
        o0.x = (u16)bf16_1(acc[0]); o0.y = (u16)bf16_1(acc[1]);
        o0.z = (u16)bf16_1(acc[2]); o0.w = (u16)bf16_1(acc[3]);
        o1.x = (u16)bf16_1(acc[4]); o1.y = (u16)bf16_1(acc[5]);
        o1.z = (u16)bf16_1(acc[6]); o1.w = (u16)bf16_1(acc[7]);
        u16* dst = gp + ((size_t)b * 256 + t) * 128 + kb;
        *(ushort4*)(dst) = o0;
        *(ushort4*)(dst + 4) = o1;
    }
}

// ---------------------------------------------------------------------------
// MFMA attention, 64-ci blocks (R10 structure, setprio variant).
// ---------------------------------------------------------------------------
__global__ __launch_bounds__(256, 4) void attn_kernel(
    const u16* __restrict__ phi,   // [B][256][9216] bf16
    const u16* __restrict__ tpT,   // [B][128][256] bf16
    const u16* __restrict__ gp,    // [B][256][128] bf16
    u16* __restrict__ y2T)         // [B][9216 hw'][256 ci] bf16
{
    __shared__ __align__(16) char smem[40960];
    u16* As = (u16*)smem;
    u16* Bs = (u16*)(smem + 8192);
    char* Pb = smem + 24576;
    u16* Gs = (u16*)smem;

    const int t = threadIdx.x;
    const int w = t >> 6, l = t & 63;
    const int g = l >> 4, li = l & 15;
    const int b = blockIdx.y;
    const int rr = blockIdx.x >> 2;
    const int ci0 = (blockIdx.x & 3) << 6;

    const u16* phib = phi + (size_t)b * (OIN * HWN);
    const u16* tpb  = tpT + (size_t)b * (128 * 256);
    const u16* gpb  = gp  + (size_t)b * (256 * 128);

    const int srow = t >> 3;
    const int su = t & 7;

    f32x4 zero = {0.f, 0.f, 0.f, 0.f};
    f32x4 acc[8];
#pragma unroll
    for (int j = 0; j < 8; ++j) acc[j] = zero;

    for (int kt = 0; kt < 256; kt += 64) {
#pragma unroll
        for (int cc = 0; cc < 2; ++cc) {
            int row = cc * 32 + srow;
            int ss = su ^ (row & 7);
            gload16(phib + (size_t)(ci0 + row) * HWN + rr * 256 + kt + ss * 8,
                    &As[(row * 8 + su) * 8]);
        }
#pragma unroll
        for (int cc = 0; cc < 4; ++cc) {
            int row = cc * 32 + srow;
            int ss = su ^ (row & 7);
            gload16(tpb + (size_t)row * 256 + kt + ss * 8,
                    &Bs[(row * 8 + su) * 8]);
        }
        __syncthreads();

#pragma unroll
        for (int h = 0; h < 2; ++h) {
            int r = w * 16 + li;
            bf16x8 af = *(const bf16x8*)&As[r * 64 + (((h * 4 + g) ^ (r & 7)) << 3)];
            bf16x8 bfr[8];
#pragma unroll
            for (int ni = 0; ni < 8; ++ni) {
                int rb = ni * 16 + li;
                bfr[ni] = *(const bf16x8*)&Bs[rb * 64 + (((h * 4 + g) ^ (rb & 7)) << 3)];
            }
            __builtin_amdgcn_s_setprio(1);
#pragma unroll
            for (int ni = 0; ni < 8; ++ni)
                acc[ni] = __builtin_amdgcn_mfma_f32_16x16x32_bf16(
                    af, bfr[ni], acc[ni], 0, 0, 0);
            __builtin_amdgcn_s_setprio(0);
        }
        __syncthreads();
    }

    bool vm[8];
#pragma unroll
    for (int ni = 0; ni < 8; ++ni) vm[ni] = (ni * 16 + li) < KP;

#pragma unroll
    for (int r = 0; r < 4; ++r) {
        float mx = -1e30f;
#pragma unroll
        for (int ni = 0; ni < 8; ++ni)
            if (vm[ni]) mx = fmaxf(mx, acc[ni][r] * SCL);
        mx = fmaxf(mx, __shfl_xor(mx, 1));
        mx = fmaxf(mx, __shfl_xor(mx, 2));
        mx = fmaxf(mx, __shfl_xor(mx, 4));
        mx = fmaxf(mx, __shfl_xor(mx, 8));
        float s = 0.f;
#pragma unroll
        for (int ni = 0; ni < 8; ++ni) {
            float e = vm[ni] ? __expf(acc[ni][r] * SCL - mx) : 0.f;
            acc[ni][r] = e;
            s += e;
        }
        s += __shfl_xor(s, 1);
        s += __shfl_xor(s, 2);
        s += __shfl_xor(s, 4);
        s += __shfl_xor(s, 8);
        float inv = 1.0f / s;
#pragma unroll
        for (int ni = 0; ni < 8; ++ni) acc[ni][r] *= inv;
    }
#pragma unroll
    for (int ni = 0; ni < 8; ++ni)
#pragma unroll
        for (int r = 0; r < 4; ++r) {
            int row = w * 16 + g * 4 + r;
            int col = ni * 16 + li;
            *(short*)(Pb + row * 256 + (((col >> 3) ^ (row & 7)) << 4) + ((col & 7) << 1)) =
                (short)bf16_1(acc[ni][r]);
        }

    f32x4 acc2[16];
#pragma unroll
    for (int j = 0; j < 16; ++j) acc2[j] = zero;

#pragma unroll 1
    for (int ch = 0; ch < 4; ++ch) {
#pragma unroll
        for (int j = 0; j < 4; ++j) {
            int row = j * 64 + (t >> 2);
            int slot = t & 3;
            int ss = slot ^ (row & 3);
            gload16(gpb + (size_t)row * 128 + ch * 32 + ss * 8,
                    &Gs[(j * 256 + t) * 8]);
        }
        __syncthreads();

        int prow = w * 16 + li;
        bf16x8 a2 = *(const bf16x8*)(Pb + prow * 256 + (((ch * 4 + g) ^ (prow & 7)) << 4));
        __builtin_amdgcn_s_setprio(1);
#pragma unroll
        for (int cf = 0; cf < 16; ++cf) {
            int crow = cf * 16 + li;
            bf16x8 bv = *(const bf16x8*)((const char*)Gs + crow * 64 + ((g ^ (crow & 3)) << 4));
            acc2[cf] = __builtin_amdgcn_mfma_f32_16x16x32_bf16(a2, bv, acc2[cf], 0, 0, 0);
        }
        __builtin_amdgcn_s_setprio(0);
        __syncthreads();
    }

#pragma unroll
    for (int cf = 0; cf < 16; ++cf) {
        int c = cf * 16 + li;
        int cib = w * 16 + g * 4;
        int e0 = c * 64 + (cib ^ ((li & 7) << 3));
        unsigned d0 = bf16_pack(acc2[cf][0], acc2[cf][1]);
        unsigned d1 = bf16_pack(acc2[cf][2], acc2[cf][3]);
        *(unsigned*)(smem + (size_t)e0 * 2) = d0;
        *(unsigned*)(smem + (size_t)e0 * 2 + 4) = d1;
    }

    __syncthreads();

    {
        int c = t;
        u16* dst = y2T + ((size_t)b * HWN + rr * 256 + c) * 256 + ci0;
#pragma unroll
        for (int j = 0; j < 8; ++j) {
            uint4 v = *(const uint4*)(smem + c * 128 + ((j ^ (c & 7)) << 4));
            *(uint4*)(dst + j * 8) = v;
        }
    }
}

extern "C" void kernel_launch(void* const* d_in, const int* in_sizes, int n_in,
                              void* d_out, int out_size, void* d_ws, size_t ws_size,
                              hipStream_t stream)
{
    const float* x       = (const float*)d_in[0];
    const float* phi_w   = (const float*)d_in[1];
    const float* phi_b   = (const float*)d_in[2];
    const float* theta_w = (const float*)d_in[3];
    const float* theta_b = (const float*)d_in[4];
    const float* gamma_w = (const float*)d_in[5];
    const float* gamma_b = (const float*)d_in[6];
    const float* W_w     = (const float*)d_in[7];
    const float* W_b     = (const float*)d_in[8];
    float* out = (float*)d_out;

    char* p = (char*)d_ws;
    u16* xT     = (u16*)p;  p += (size_t)NB * HWN * CIN * 2;   // 75.5 MB
    u16* phi_bf = (u16*)p;  p += (size_t)NB * OIN * HWN * 2;   // 37.7 MB
    u16* th_y2  = (u16*)p;  p += (size_t)NB * OIN * HWN * 2;   // 37.7 MB (theta, then y2T)
    float* xp   = (float*)p; p += (size_t)NB * CIN * KP * 4;
    u16* tpT    = (u16*)p;  p += (size_t)NB * 128 * 256 * 2;
    u16* gp     = (u16*)p;  p += (size_t)NB * 256 * 128 * 2;
    u16* Wcat   = (u16*)p;  p += 512 * 512 * 2;
    u16* Wwb    = (u16*)p;  p += 512 * 256 * 2;

    prep_kernel<<<dim3(14848), 256, 0, stream>>>(
        x, xT, xp, phi_w, theta_w, W_w, Wcat, Wwb);
    gemm_kernel<512, 0><<<dim3(72 * 4 * NB), 256, 0, stream>>>(
        xT, Wcat, phi_b, theta_b, nullptr, phi_bf, th_y2);
    mid_kernel<<<dim3(2176), 256, 0, stream>>>(
        th_y2, tpT, xp, gamma_w, gamma_b, gp);
    attn_kernel<<<dim3(144, NB), 256, 0, stream>>>(phi_bf, tpT, gp, th_y2);
    gemm_kernel<256, 1><<<dim3(72 * 4 * NB), 256, 0, stream>>>(
        th_y2, Wwb, W_b, nullptr, x, out, nullptr);
}

// Round 20
// 281.129 us; speedup vs baseline: 1.1405x; 1.0161x over previous
//
#include <hip/hip_runtime.h>

#define NB 8
#define CIN 512
#define OIN 256
#define HWN 9216
#define KP 110
#define SCL 0.10206207261596577f  // 9216^(-0.25)

typedef __attribute__((ext_vector_type(8))) short bf16x8;
typedef __attribute__((ext_vector_type(4))) float f32x4;
typedef unsigned short u16;

__device__ inline unsigned bf16_1(float a) {
    unsigned u = __builtin_bit_cast(unsigned, a);
    return (u + 0x7fffu + ((u >> 16) & 1u)) >> 16;
}
__device__ inline unsigned bf16_pack(float a, float b) {
    return bf16_1(a) | (bf16_1(b) << 16);
}
__device__ inline float b2f(u16 u) {
    return __builtin_bit_cast(float, ((unsigned)u) << 16);
}

__device__ __forceinline__ void gload16(const u16* g, u16* l) {
    __builtin_amdgcn_global_load_lds(
        (const __attribute__((address_space(1))) unsigned int*)g,
        (__attribute__((address_space(3))) unsigned int*)l, 16, 0, 0);
}

// ---------------------------------------------------------------------------
// prep: fused castw + castx + pool_x.
// castx: 64c x 256hw per block (1KB-contiguous reads per c-row, 16 loads
// in flight per thread), LDS-bounced transpose, coalesced 128B stores.
// pool_x: k==0 global sum now wave-cooperative (was 576-iter serial chain).
// grid = 2304 (castx) + 4096 (pool_x) + 1536 (castw) = 7936 blocks.
// ---------------------------------------------------------------------------
__global__ __launch_bounds__(256) void prep_kernel(
    const float* __restrict__ x, u16* __restrict__ xT, float* __restrict__ xp,
    const float* __restrict__ phi_w, const float* __restrict__ theta_w,
    const float* __restrict__ Ww,
    u16* __restrict__ Wcat, u16* __restrict__ Wwb)
{
    __shared__ __align__(16) char sh[32768];
    const int bid = blockIdx.x;
    const int t = threadIdx.x;

    if (bid < 2304) {
        // ---- castx: x fp32 [b][512][9216] -> xT bf16 [b][9216][512] ----
        const int bx = bid % 36;
        const int cy = (bid / 36) & 7;
        const int b = bid / 288;
        const int tx = t & 15, ty = t >> 4;
        const int c0 = cy * 64;
        const int hw0 = bx * 256;

        // phase 0: 16 independent float4 loads (4 c-rows x 4 hw-chunks)
        const float* xb = x + ((size_t)b * CIN + c0 + ty * 4) * HWN + hw0 + tx * 4;
        float4 v[4][4];
#pragma unroll
        for (int h = 0; h < 4; ++h)
#pragma unroll
            for (int q = 0; q < 4; ++q)
                v[h][q] = *(const float4*)(xb + (size_t)q * HWN + h * 64);

        // phase 1: transpose into LDS [256 hw][16 slots x 8B], XOR swizzle
        u16* ld = (u16*)sh;
        const int sb = (tx & 7) * 2;
        const int sl = ty ^ sb;
#pragma unroll
        for (int h = 0; h < 4; ++h) {
            const float* f = (const float*)v[h];
#pragma unroll
            for (int i = 0; i < 4; ++i) {
                int row = h * 64 + tx * 4 + i;
                uint2 o = {bf16_pack(f[0 * 4 + i], f[1 * 4 + i]),
                           bf16_pack(f[2 * 4 + i], f[3 * 4 + i])};
                *(uint2*)((char*)ld + row * 128 + sl * 8) = o;
            }
        }
        __syncthreads();

        // phase 2: coalesced stores, 8 lanes x uint4 = 128B per row segment
        const int row0 = t >> 3, p = t & 7;
#pragma unroll
        for (int jj = 0; jj < 8; ++jj) {
            int row = row0 + jj * 32;
            uint4 w = *(const uint4*)((char*)ld + row * 128 + 16 * (p ^ ((row >> 2) & 7)));
            *(uint4*)(xT + ((size_t)b * HWN + hw0 + row) * CIN + c0 + p * 8) = w;
        }
    } else if (bid < 6400) {
        // ---- pool_x: x fp32 plane -> xp [plane][110] ----
        float* ps = (float*)sh;          // 576 floats
        float* psw = ps + 576;           // 4 per-wave partials
        const int plane = bid - 2304;
        const float* p = x + (size_t)plane * HWN;

        for (int i = t; i < 576; i += 256) {
            int bh = i / 24, bw = i % 24;
            float s = 0.f;
#pragma unroll
            for (int r = 0; r < 4; ++r) {
                float4 v = *(const float4*)&p[(bh * 4 + r) * 96 + bw * 4];
                s += v.x + v.y + v.z + v.w;
            }
            ps[i] = s;
        }
        __syncthreads();

        // cooperative global sum (for bin k==0)
        {
            float part = ps[t] + ps[t + 256] + ((t < 64) ? ps[t + 512] : 0.f);
#pragma unroll
            for (int off = 32; off; off >>= 1) part += __shfl_xor(part, off, 64);
            if ((t & 63) == 0) psw[t >> 6] = part;
        }
        __syncthreads();

        if (t < KP) {
            float s = 0.f;
            if (t == 0) {
                s = (psw[0] + psw[1] + psw[2] + psw[3]) * (1.0f / 9216.0f);
            } else if (t < 10) {
                int idx = t - 1, bi = idx / 3, bj = idx % 3;
                for (int r = 0; r < 8; ++r)
                    for (int c = 0; c < 8; ++c)
                        s += ps[(bi * 8 + r) * 24 + bj * 8 + c];
                s *= (1.0f / 1024.0f);
            } else if (t < 46) {
                int idx = t - 10, bi = idx / 6, bj = idx % 6;
                for (int r = 0; r < 4; ++r)
                    for (int c = 0; c < 4; ++c)
                        s += ps[(bi * 4 + r) * 24 + bj * 4 + c];
                s *= (1.0f / 256.0f);
            } else {
                int idx = t - 46, bi = idx / 8, bj = idx % 8;
                for (int r = 0; r < 3; ++r)
                    for (int c = 0; c < 3; ++c)
                        s += ps[(bi * 3 + r) * 24 + bj * 3 + c];
                s *= (1.0f / 144.0f);
            }
            xp[(size_t)plane * KP + t] = s;
        }
    } else {
        // ---- castw ----
        int i = (bid - 6400) * 256 + t;
        if (i < 262144) {
            float v = (i < 131072) ? phi_w[i] : theta_w[i - 131072];
            Wcat[i] = (u16)bf16_1(v);
        } else {
            int j = i - 262144;
            Wwb[j] = (u16)bf16_1(Ww[j]);
        }
    }
}

// ---------------------------------------------------------------------------
// MFMA GEMM (proven R11 structure): BK=32, 3 buffers, counted vmcnt,
// 48 KB LDS, 3 blocks/CU. slot ^ ((row>>1)&3) swizzle -> <=2-way LDS aliasing.
// ---------------------------------------------------------------------------
template<int KDIM, int MODE>
__global__ __launch_bounds__(256, 3) void gemm_kernel(
    const u16* __restrict__ A,
    const u16* __restrict__ Bw,
    const float* __restrict__ b0, const float* __restrict__ b1,
    const float* __restrict__ resid,
    void* __restrict__ out0_, void* __restrict__ out1_)
{
    __shared__ u16 As[3][128 * 32];
    __shared__ u16 Bs[3][128 * 32];

    constexpr int NSTEP = KDIM / 32;
    constexpr int NWG = 72 * 4 * NB;

    const int id = blockIdx.x;
    const int swz = (id & 7) * (NWG / 8) + (id >> 3);
    const int u = swz % 288;
    const int bz = swz / 288;
    const int by = u & 3;
    const int bx = u >> 2;

    const int t = threadIdx.x;
    const int m0 = bx * 128;
    const int n0 = by * 128;
    const int w = t >> 6, l = t & 63;
    const int wr = w >> 1, wc = w & 1;
    const int g = l >> 4, li = l & 15;

    const u16* Ab = A + (size_t)bz * HWN * KDIM + (size_t)m0 * KDIM;
    const u16* Bb = Bw + (size_t)n0 * KDIM;

    f32x4 zero = {0.f, 0.f, 0.f, 0.f};
    f32x4 acc[4][4];
#pragma unroll
    for (int i = 0; i < 4; ++i)
#pragma unroll
        for (int j = 0; j < 4; ++j) acc[i][j] = zero;

    auto stage = [&](int step) {
        const int buf = step % 3;
#pragma unroll
        for (int j = 0; j < 2; ++j) {
            int c = j * 256 + t;
            int row = c >> 2, slot = c & 3;
            int ss = slot ^ ((row >> 1) & 3);
            gload16(Ab + (size_t)row * KDIM + step * 32 + ss * 8, &As[buf][c * 8]);
        }
#pragma unroll
        for (int j = 0; j < 2; ++j) {
            int c = j * 256 + t;
            int row = c >> 2, slot = c & 3;
            int ss = slot ^ ((row >> 1) & 3);
            gload16(Bb + (size_t)row * KDIM + step * 32 + ss * 8, &Bs[buf][c * 8]);
        }
    };

    stage(0);
    stage(1);

#pragma unroll 1
    for (int s = 0; s < NSTEP; ++s) {
        if (s + 2 < NSTEP) {
            stage(s + 2);
            asm volatile("s_waitcnt vmcnt(8)" ::: "memory");
        } else if (s + 1 < NSTEP) {
            asm volatile("s_waitcnt vmcnt(4)" ::: "memory");
        } else {
            asm volatile("s_waitcnt vmcnt(0)" ::: "memory");
        }
        __builtin_amdgcn_s_barrier();
        __builtin_amdgcn_sched_barrier(0);

        const int cb = s % 3;
        bf16x8 af[4], bv[4];
#pragma unroll
        for (int mi = 0; mi < 4; ++mi) {
            int r = wr * 64 + mi * 16 + li;
            int sl = g ^ ((r >> 1) & 3);
            af[mi] = *(const bf16x8*)&As[cb][r * 32 + sl * 8];
        }
#pragma unroll
        for (int ni = 0; ni < 4; ++ni) {
            int r = wc * 64 + ni * 16 + li;
            int sl = g ^ ((r >> 1) & 3);
            bv[ni] = *(const bf16x8*)&Bs[cb][r * 32 + sl * 8];
        }
#pragma unroll
        for (int mi = 0; mi < 4; ++mi)
#pragma unroll
            for (int ni = 0; ni < 4; ++ni)
                acc[mi][ni] = __builtin_amdgcn_mfma_f32_16x16x32_bf16(
                    af[mi], bv[ni], acc[mi][ni], 0, 0, 0);

        __builtin_amdgcn_s_barrier();
    }

#pragma unroll
    for (int ni = 0; ni < 4; ++ni) {
        int n = n0 + wc * 64 + ni * 16 + li;
        if constexpr (MODE == 0) {
            float bias = (n < 256) ? b0[n] : b1[n - 256];
            u16* dst = (u16*)((n < 256) ? out0_ : out1_) + ((size_t)bz * 256 + (n & 255)) * HWN;
#pragma unroll
            for (int mi = 0; mi < 4; ++mi) {
                int m = m0 + wr * 64 + mi * 16 + (g << 2);
                f32x4 v = acc[mi][ni];
                float e0 = fmaxf(v.x + bias, 0.f), e1 = fmaxf(v.y + bias, 0.f);
                float e2 = fmaxf(v.z + bias, 0.f), e3 = fmaxf(v.w + bias, 0.f);
                uint2 pk = {bf16_pack(e0, e1), bf16_pack(e2, e3)};
                *(uint2*)(dst + m) = pk;
            }
        } else {
            float bias = b0[n];
            float* dst = (float*)out0_ + ((size_t)bz * 512 + n) * HWN;
            const float* res = resid + ((size_t)bz * 512 + n) * HWN;
#pragma unroll
            for (int mi = 0; mi < 4; ++mi) {
                int m = m0 + wr * 64 + mi * 16 + (g << 2);
                f32x4 v = acc[mi][ni];
                float4 rx = *(const float4*)(res + m);
                float4 o = {v.x + bias + rx.x, v.y + bias + rx.y,
                            v.z + bias + rx.z, v.w + bias + rx.w};
                *(float4*)(dst + m) = o;
            }
        }
    }
}

// ---------------------------------------------------------------------------
// mid: fused pool_t + gammap (both independent; inputs ready after gemm0).
// ---------------------------------------------------------------------------
__global__ __launch_bounds__(256) void mid_kernel(
    const u16* __restrict__ theta_bf, u16* __restrict__ tpT,
    const float* __restrict__ xp, const float* __restrict__ gw,
    const float* __restrict__ gb, u16* __restrict__ gp)
{
    __shared__ __align__(16) char sh[16384];
    const int bid = blockIdx.x;
    const int t = threadIdx.x;

    if (bid < 2048) {
        float* ps = (float*)sh;
        const int b = bid >> 8, c = bid & 255;
        const u16* p = theta_bf + (size_t)bid * HWN;

        for (int i = t; i < 576; i += 256) {
            int bh = i / 24, bw = i % 24;
            float s = 0.f;
#pragma unroll
            for (int r = 0; r < 4; ++r) {
                ushort4 v = *(const ushort4*)&p[(bh * 4 + r) * 96 + bw * 4];
                s += b2f(v.x) + b2f(v.y) + b2f(v.z) + b2f(v.w);
            }
            ps[i] = s;
        }
        __syncthreads();

        if (t < 128) {
            float s = 0.f;
            if (t == 0) {
                for (int i = 0; i < 576; ++i) s += ps[i];
                s *= (1.0f / 9216.0f);
            } else if (t < 10) {
                int idx = t - 1, bi = idx / 3, bj = idx % 3;
                for (int r = 0; r < 8; ++r)
                    for (int cc = 0; cc < 8; ++cc)
                        s += ps[(bi * 8 + r) * 24 + bj * 8 + cc];
                s *= (1.0f / 1024.0f);
            } else if (t < 46) {
                int idx = t - 10, bi = idx / 6, bj = idx % 6;
                for (int r = 0; r < 4; ++r)
                    for (int cc = 0; cc < 4; ++cc)
                        s += ps[(bi * 4 + r) * 24 + bj * 4 + cc];
                s *= (1.0f / 256.0f);
            } else if (t < KP) {
                int idx = t - 46, bi = idx / 8, bj = idx % 8;
                for (int r = 0; r < 3; ++r)
                    for (int cc = 0; cc < 3; ++cc)
                        s += ps[(bi * 3 + r) * 24 + bj * 3 + cc];
                s *= (1.0f / 144.0f);
            } else {
                s = 0.f;
            }
            tpT[((size_t)b * 128 + t) * 256 + c] = (u16)bf16_1(s);
        }
    } else {
        float (*xc)[512] = (float (*)[512])sh;
        const int gidx = bid - 2048;
        const int kb = (gidx & 15) * 8, b = gidx >> 4;

#pragma unroll
        for (int j = 0; j < 16; ++j) {
            int idx = j * 256 + t;
            int kk = idx >> 9, c = idx & 511;
            int k = kb + kk;
            xc[kk][c] = (k < KP) ? xp[((size_t)b * CIN + c) * KP + k] : 0.f;
        }
        __syncthreads();

        float bias = gb[t];
        float acc[8];
#pragma unroll
        for (int kk = 0; kk < 8; ++kk) acc[kk] = bias;

        const float* wrow = gw + (size_t)t * CIN;
#pragma unroll 2
        for (int c = 0; c < CIN; c += 4) {
            float4 wv = *(const float4*)&wrow[c];
#pragma unroll
            for (int kk = 0; kk < 8; ++kk) {
                acc[kk] = fmaf(wv.x, xc[kk][c], acc[kk]);
                acc[kk] = fmaf(wv.y, xc[kk][c + 1], acc[kk]);
                acc[kk] = fmaf(wv.z, xc[kk][c + 2], acc[kk]);
                acc[kk] = fmaf(wv.w, xc[kk][c + 3], acc[kk]);
            }
        }

        ushort4 o0, o1;
        o0.x = (u16)bf16_1(acc[0]); o0.y = (u16)bf16_1(acc[1]);
        o0.z = (u16)bf16_1(acc[2]); o0.w = (u16)bf16_1(acc[3]);
        o1.x = (u16)bf16_1(acc[4]); o1.y = (u16)bf16_1(acc[5]);
        o1.z = (u16)bf16_1(acc[6]); o1.w = (u16)bf16_1(acc[7]);
        u16* dst = gp + ((size_t)b * 256 + t) * 128 + kb;
        *(ushort4*)(dst) = o0;
        *(ushort4*)(dst + 4) = o1;
    }
}

// ---------------------------------------------------------------------------
// MFMA attention, 64-ci blocks (R10 structure, setprio variant).
// ---------------------------------------------------------------------------
__global__ __launch_bounds__(256, 4) void attn_kernel(
    const u16* __restrict__ phi,   // [B][256][9216] bf16
    const u16* __restrict__ tpT,   // [B][128][256] bf16
    const u16* __restrict__ gp,    // [B][256][128] bf16
    u16* __restrict__ y2T)         // [B][9216 hw'][256 ci] bf16
{
    __shared__ __align__(16) char smem[40960];
    u16* As = (u16*)smem;
    u16* Bs = (u16*)(smem + 8192);
    char* Pb = smem + 24576;
    u16* Gs = (u16*)smem;

    const int t = threadIdx.x;
    const int w = t >> 6, l = t & 63;
    const int g = l >> 4, li = l & 15;
    const int b = blockIdx.y;
    const int rr = blockIdx.x >> 2;
    const int ci0 = (blockIdx.x & 3) << 6;

    const u16* phib = phi + (size_t)b * (OIN * HWN);
    const u16* tpb  = tpT + (size_t)b * (128 * 256);
    const u16* gpb  = gp  + (size_t)b * (256 * 128);

    const int srow = t >> 3;
    const int su = t & 7;

    f32x4 zero = {0.f, 0.f, 0.f, 0.f};
    f32x4 acc[8];
#pragma unroll
    for (int j = 0; j < 8; ++j) acc[j] = zero;

    for (int kt = 0; kt < 256; kt += 64) {
#pragma unroll
        for (int cc = 0; cc < 2; ++cc) {
            int row = cc * 32 + srow;
            int ss = su ^ (row & 7);
            gload16(phib + (size_t)(ci0 + row) * HWN + rr * 256 + kt + ss * 8,
                    &As[(row * 8 + su) * 8]);
        }
#pragma unroll
        for (int cc = 0; cc < 4; ++cc) {
            int row = cc * 32 + srow;
            int ss = su ^ (row & 7);
            gload16(tpb + (size_t)row * 256 + kt + ss * 8,
                    &Bs[(row * 8 + su) * 8]);
        }
        __syncthreads();

#pragma unroll
        for (int h = 0; h < 2; ++h) {
            int r = w * 16 + li;
            bf16x8 af = *(const bf16x8*)&As[r * 64 + (((h * 4 + g) ^ (r & 7)) << 3)];
            bf16x8 bfr[8];
#pragma unroll
            for (int ni = 0; ni < 8; ++ni) {
                int rb = ni * 16 + li;
                bfr[ni] = *(const bf16x8*)&Bs[rb * 64 + (((h * 4 + g) ^ (rb & 7)) << 3)];
            }
            __builtin_amdgcn_s_setprio(1);
#pragma unroll
            for (int ni = 0; ni < 8; ++ni)
                acc[ni] = __builtin_amdgcn_mfma_f32_16x16x32_bf16(
                    af, bfr[ni], acc[ni], 0, 0, 0);
            __builtin_amdgcn_s_setprio(0);
        }
        __syncthreads();
    }

    bool vm[8];
#pragma unroll
    for (int ni = 0; ni < 8; ++ni) vm[ni] = (ni * 16 + li) < KP;

#pragma unroll
    for (int r = 0; r < 4; ++r) {
        float mx = -1e30f;
#pragma unroll
        for (int ni = 0; ni < 8; ++ni)
            if (vm[ni]) mx = fmaxf(mx, acc[ni][r] * SCL);
        mx = fmaxf(mx, __shfl_xor(mx, 1));
        mx = fmaxf(mx, __shfl_xor(mx, 2));
        mx = fmaxf(mx, __shfl_xor(mx, 4));
        mx = fmaxf(mx, __shfl_xor(mx, 8));
        float s = 0.f;
#pragma unroll
        for (int ni = 0; ni < 8; ++ni) {
            float e = vm[ni] ? __expf(acc[ni][r] * SCL - mx) : 0.f;
            acc[ni][r] = e;
            s += e;
        }
        s += __shfl_xor(s, 1);
        s += __shfl_xor(s, 2);
        s += __shfl_xor(s, 4);
        s += __shfl_xor(s, 8);
        float inv = 1.0f / s;
#pragma unroll
        for (int ni = 0; ni < 8; ++ni) acc[ni][r] *= inv;
    }
#pragma unroll
    for (int ni = 0; ni < 8; ++ni)
#pragma unroll
        for (int r = 0; r < 4; ++r) {
            int row = w * 16 + g * 4 + r;
            int col = ni * 16 + li;
            *(short*)(Pb + row * 256 + (((col >> 3) ^ (row & 7)) << 4) + ((col & 7) << 1)) =
                (short)bf16_1(acc[ni][r]);
        }

    f32x4 acc2[16];
#pragma unroll
    for (int j = 0; j < 16; ++j) acc2[j] = zero;

#pragma unroll 1
    for (int ch = 0; ch < 4; ++ch) {
#pragma unroll
        for (int j = 0; j < 4; ++j) {
            int row = j * 64 + (t >> 2);
            int slot = t & 3;
            int ss = slot ^ (row & 3);
            gload16(gpb + (size_t)row * 128 + ch * 32 + ss * 8,
                    &Gs[(j * 256 + t) * 8]);
        }
        __syncthreads();

        int prow = w * 16 + li;
        bf16x8 a2 = *(const bf16x8*)(Pb + prow * 256 + (((ch * 4 + g) ^ (prow & 7)) << 4));
        __builtin_amdgcn_s_setprio(1);
#pragma unroll
        for (int cf = 0; cf < 16; ++cf) {
            int crow = cf * 16 + li;
            bf16x8 bv = *(const bf16x8*)((const char*)Gs + crow * 64 + ((g ^ (crow & 3)) << 4));
            acc2[cf] = __builtin_amdgcn_mfma_f32_16x16x32_bf16(a2, bv, acc2[cf], 0, 0, 0);
        }
        __builtin_amdgcn_s_setprio(0);
        __syncthreads();
    }

#pragma unroll
    for (int cf = 0; cf < 16; ++cf) {
        int c = cf * 16 + li;
        int cib = w * 16 + g * 4;
        int e0 = c * 64 + (cib ^ ((li & 7) << 3));
        unsigned d0 = bf16_pack(acc2[cf][0], acc2[cf][1]);
        unsigned d1 = bf16_pack(acc2[cf][2], acc2[cf][3]);
        *(unsigned*)(smem + (size_t)e0 * 2) = d0;
        *(unsigned*)(smem + (size_t)e0 * 2 + 4) = d1;
    }

    __syncthreads();

    {
        int c = t;
        u16* dst = y2T + ((size_t)b * HWN + rr * 256 + c) * 256 + ci0;
#pragma unroll
        for (int j = 0; j < 8; ++j) {
            uint4 v = *(const uint4*)(smem + c * 128 + ((j ^ (c & 7)) << 4));
            *(uint4*)(dst + j * 8) = v;
        }
    }
}

extern "C" void kernel_launch(void* const* d_in, const int* in_sizes, int n_in,
                              void* d_out, int out_size, void* d_ws, size_t ws_size,
                              hipStream_t stream)
{
    const float* x       = (const float*)d_in[0];
    const float* phi_w   = (const float*)d_in[1];
    const float* phi_b   = (const float*)d_in[2];
    const float* theta_w = (const float*)d_in[3];
    const float* theta_b = (const float*)d_in[4];
    const float* gamma_w = (const float*)d_in[5];
    const float* gamma_b = (const float*)d_in[6];
    const float* W_w     = (const float*)d_in[7];
    const float* W_b     = (const float*)d_in[8];
    float* out = (float*)d_out;

    char* p = (char*)d_ws;
    u16* xT     = (u16*)p;  p += (size_t)NB * HWN * CIN * 2;   // 75.5 MB
    u16* phi_bf = (u16*)p;  p += (size_t)NB * OIN * HWN * 2;   // 37.7 MB
    u16* th_y2  = (u16*)p;  p += (size_t)NB * OIN * HWN * 2;   // 37.7 MB (theta, then y2T)
    float* xp   = (float*)p; p += (size_t)NB * CIN * KP * 4;
    u16* tpT    = (u16*)p;  p += (size_t)NB * 128 * 256 * 2;
    u16* gp     = (u16*)p;  p += (size_t)NB * 256 * 128 * 2;
    u16* Wcat   = (u16*)p;  p += 512 * 512 * 2;
    u16* Wwb    = (u16*)p;  p += 512 * 256 * 2;

    prep_kernel<<<dim3(7936), 256, 0, stream>>>(
        x, xT, xp, phi_w, theta_w, W_w, Wcat, Wwb);
    gemm_kernel<512, 0><<<dim3(72 * 4 * NB), 256, 0, stream>>>(
        xT, Wcat, phi_b, theta_b, nullptr, phi_bf, th_y2);
    mid_kernel<<<dim3(2176), 256, 0, stream>>>(
        th_y2, tpT, xp, gamma_w, gamma_b, gp);
    attn_kernel<<<dim3(144, NB), 256, 0, stream>>>(phi_bf, tpT, gp, th_y2);
    gemm_kernel<256, 1><<<dim3(72 * 4 * NB), 256, 0, stream>>>(
        th_y2, Wwb, W_b, nullptr, x, out, nullptr);
}